// Round 4
// baseline (699.276 us; speedup 1.0000x reference)
//
#include <hip/hip_runtime.h>
#include <math.h>

#define BS 256
#define LQ 256
#define KN 64
#define BH 512
#define SUB_IN 1537

typedef __attribute__((ext_vector_type(8))) short bf16x8;
typedef __attribute__((ext_vector_type(4))) float f32x4;

__device__ __forceinline__ float clip15(float x) {
  return fminf(fmaxf(x, -15.f), 15.f);
}
__device__ __forceinline__ short f2bf(float f) {
  unsigned u = __float_as_uint(f);
  u = u + 0x7fffu + ((u >> 16) & 1u);
  return (short)(u >> 16);
}
__device__ __forceinline__ float bf2f(short s) {
  return __uint_as_float(((unsigned)(unsigned short)s) << 16);
}

// XOR swizzle on the 16B slot within each 128B LDS row (proven R2/R3)
#define SWZ(row, byte) ((byte) ^ (((((row) ^ ((row) >> 3)) & 7)) << 4))

// ---------------- small prep kernels ----------------

__global__ void k_cvt(const float* __restrict__ in, short* __restrict__ out, int n4) {
  int i = blockIdx.x * blockDim.x + threadIdx.x;
  if (i >= n4) return;
  f32x4 v = ((const f32x4*)in)[i];
  ((short4*)out)[i] = make_short4(f2bf(v[0]), f2bf(v[1]), f2bf(v[2]), f2bf(v[3]));
}

__global__ void k_cvt_scaled(const float* __restrict__ in, const float* __restrict__ w,
                             short* __restrict__ out, int n4) {
  int i = blockIdx.x * blockDim.x + threadIdx.x;
  if (i >= n4) return;
  int d4 = i & (BH / 4 - 1);
  f32x4 v = ((const f32x4*)in)[i];
  f32x4 wv = ((const f32x4*)w)[d4];
  v = v * wv;
  ((short4*)out)[i] = make_short4(f2bf(v[0]), f2bf(v[1]), f2bf(v[2]), f2bf(v[3]));
}

// prjT[n][k] = bf16(prj[k][n]); k=2048, n=512
__global__ void k_prjT(const float* __restrict__ prj, short* __restrict__ prjT) {
  __shared__ float t[32][33];
  int k0 = blockIdx.x * 32, n0 = blockIdx.y * 32;
  int x = threadIdx.x & 31, y = threadIdx.x >> 5;  // 32x8
  for (int yy = y; yy < 32; yy += 8)
    t[yy][x] = prj[(size_t)(k0 + yy) * BH + n0 + x];
  __syncthreads();
  for (int yy = y; yy < 32; yy += 8)
    prjT[(size_t)(n0 + yy) * 2048 + k0 + x] = f2bf(t[x][yy]);
}

__global__ void k_rowdot(const float* __restrict__ X, const float* __restrict__ w,
                         float* __restrict__ out, int rows) {
  int row = blockIdx.x * 4 + (threadIdx.x >> 6);
  int lane = threadIdx.x & 63;
  if (row >= rows) return;
  const float* x = X + (size_t)row * BH;
  float s = 0.f;
#pragma unroll
  for (int i = 0; i < BH; i += 64) s = fmaf(x[i + lane], w[i + lane], s);
#pragma unroll
  for (int off = 32; off; off >>= 1) s += __shfl_down(s, off);
  if (lane == 0) out[row] = s;
}

// ---------------- staging helpers (64x64 bf16 tile into SWZ'd LDS) ----------------

__device__ __forceinline__ void stage_nat(const short* __restrict__ src, size_t ld,
                                          short* As, int tid) {
  int kl = (tid & 15) * 4;
#pragma unroll
  for (int it = 0; it < 4; ++it) {
    int row = (tid >> 4) + it * 16;
    short4 v = *(const short4*)(src + (size_t)row * ld + kl);
    *(short4*)((char*)As + SWZ(row, row * 128 + kl * 2)) = v;
  }
}

// transposed: bf16 source [k][n] (stride ld) -> Bs[n][k]
__device__ __forceinline__ void stage_tr(const short* __restrict__ src, size_t ld,
                                         short* Bs, int tid) {
  int n0 = (tid & 15) * 4;
  int k0 = (tid >> 4) * 4;
  short4 r0 = *(const short4*)(src + (size_t)(k0 + 0) * ld + n0);
  short4 r1 = *(const short4*)(src + (size_t)(k0 + 1) * ld + n0);
  short4 r2 = *(const short4*)(src + (size_t)(k0 + 2) * ld + n0);
  short4 r3 = *(const short4*)(src + (size_t)(k0 + 3) * ld + n0);
  *(short4*)((char*)Bs + SWZ(n0 + 0, (n0 + 0) * 128 + k0 * 2)) = make_short4(r0.x, r1.x, r2.x, r3.x);
  *(short4*)((char*)Bs + SWZ(n0 + 1, (n0 + 1) * 128 + k0 * 2)) = make_short4(r0.y, r1.y, r2.y, r3.y);
  *(short4*)((char*)Bs + SWZ(n0 + 2, (n0 + 2) * 128 + k0 * 2)) = make_short4(r0.z, r1.z, r2.z, r3.z);
  *(short4*)((char*)Bs + SWZ(n0 + 3, (n0 + 3) * 128 + k0 * 2)) = make_short4(r0.w, r1.w, r2.w, r3.w);
}

// wave computes 16 rows (m0..m0+15) x 64 cols of a 64x64 tile
__device__ __forceinline__ void mfma64(const short* As, const short* Bs,
                                       f32x4 acc[4], int lane, int m0) {
#pragma unroll
  for (int kb = 0; kb < 2; ++kb) {
    int k16 = kb * 32 + (lane >> 4) * 8;
    int arow = m0 + (lane & 15);
    bf16x8 af = *(const bf16x8*)((const char*)As + SWZ(arow, arow * 128 + k16 * 2));
#pragma unroll
    for (int f = 0; f < 4; ++f) {
      int nrow = f * 16 + (lane & 15);
      bf16x8 bfr = *(const bf16x8*)((const char*)Bs + SWZ(nrow, nrow * 128 + k16 * 2));
      acc[f] = __builtin_amdgcn_mfma_f32_16x16x32_bf16(af, bfr, acc[f], 0, 0, 0);
    }
  }
}

// ---------------- MFMA pipeline kernels ----------------

// S[b,c,q] = sum_d Cw[c,d]*Q[q,d] + cw[c] + qw[q] + bias
// Fused epilogue: S2 = masked_softmax over c (cmask), written as bf16.
__global__ void k_score_mfma(const short* __restrict__ Cw, const short* __restrict__ Qbf,
                             const float* __restrict__ cw, const float* __restrict__ qw,
                             const float* __restrict__ bias, const float* __restrict__ cmask,
                             float* __restrict__ S, short* __restrict__ S2) {
  const int b = blockIdx.x, q0 = blockIdx.y * 64;
  const int tid = threadIdx.x, lane = tid & 63, wave = tid >> 6, m0 = wave * 16;
  __shared__ __align__(16) short As[2][64 * 64];
  __shared__ __align__(16) short Bs[2][64 * 64];
  f32x4 acc[4] = {};
  const short* Cb = Cw + (size_t)b * KN * BH;
  const short* Qb = Qbf + ((size_t)b * LQ + q0) * BH;
  for (int kk = 0; kk < BH; kk += 128) {
    stage_nat(Cb + kk, BH, As[0], tid);
    stage_nat(Cb + kk + 64, BH, As[1], tid);
    stage_nat(Qb + kk, BH, Bs[0], tid);
    stage_nat(Qb + kk + 64, BH, Bs[1], tid);
    __syncthreads();
    mfma64(As[0], Bs[0], acc, lane, m0);
    mfma64(As[1], Bs[1], acc, lane, m0);
    __syncthreads();
  }
  const float bv = bias[0];
  const int l15 = lane & 15, g4 = lane >> 4;
  float sraw[4][4], xv[4][4], cmv[4], cwv[4];
#pragma unroll
  for (int e = 0; e < 4; ++e) {
    int c = m0 + g4 * 4 + e;
    cmv[e] = cmask[b * KN + c];
    cwv[e] = cw[b * KN + c];
  }
#pragma unroll
  for (int f = 0; f < 4; ++f) {
    int q = q0 + f * 16 + l15;
    float qv = qw[b * LQ + q] + bv;
#pragma unroll
    for (int e = 0; e < 4; ++e) {
      sraw[f][e] = acc[f][e] + cwv[e] + qv;
      xv[f][e] = clip15(sraw[f][e]) * cmv[e];
    }
  }
  float* red = (float*)As;  // [wave][f][l15] -> 4*4*16 floats (1 KB), reuse LDS
  // ---- column max over c ----
  float wm[4];
#pragma unroll
  for (int f = 0; f < 4; ++f) {
    float m = fmaxf(fmaxf(xv[f][0], xv[f][1]), fmaxf(xv[f][2], xv[f][3]));
    m = fmaxf(m, __shfl_xor(m, 16));
    m = fmaxf(m, __shfl_xor(m, 32));
    wm[f] = m;
  }
  if (g4 == 0) {
#pragma unroll
    for (int f = 0; f < 4; ++f) red[(wave * 4 + f) * 16 + l15] = wm[f];
  }
  __syncthreads();
  float cmax[4];
#pragma unroll
  for (int f = 0; f < 4; ++f) {
    float m = red[f * 16 + l15];
#pragma unroll
    for (int w2 = 1; w2 < 4; ++w2) m = fmaxf(m, red[(w2 * 4 + f) * 16 + l15]);
    cmax[f] = m;
  }
  __syncthreads();
  // ---- column sum ----
  float wsum[4];
#pragma unroll
  for (int f = 0; f < 4; ++f) {
    float s = 0.f;
#pragma unroll
    for (int e = 0; e < 4; ++e) s += __expf(xv[f][e] - cmax[f]) * cmv[e];
    s += __shfl_xor(s, 16);
    s += __shfl_xor(s, 32);
    wsum[f] = s;
  }
  if (g4 == 0) {
#pragma unroll
    for (int f = 0; f < 4; ++f) red[(wave * 4 + f) * 16 + l15] = wsum[f];
  }
  __syncthreads();
#pragma unroll
  for (int f = 0; f < 4; ++f) {
    float s = 0.f;
#pragma unroll
    for (int w2 = 0; w2 < 4; ++w2) s += red[(w2 * 4 + f) * 16 + l15];
    float inv = 1.f / (s + 1e-6f);
    int q = q0 + f * 16 + l15;
#pragma unroll
    for (int e = 0; e < 4; ++e) {
      int c = m0 + g4 * 4 + e;
      S[((size_t)b * KN + c) * LQ + q] = sraw[f][e];
      S2[((size_t)b * KN + c) * LQ + q] = f2bf(__expf(xv[f][e] - cmax[f]) * cmv[e] * inv);
    }
  }
}

__global__ void k_softmax_q(const float* __restrict__ S, const float* __restrict__ qmask,
                            short* __restrict__ S1) {
  int row = blockIdx.x * 4 + (threadIdx.x >> 6);
  int lane = threadIdx.x & 63;
  int b = row >> 6;
  const float4* Sr = (const float4*)(S + (size_t)row * LQ);
  const float4* Qm = (const float4*)(qmask + (size_t)b * LQ);
  float4 xvv = Sr[lane];
  float4 mv = Qm[lane];
  float xa[4] = {xvv.x, xvv.y, xvv.z, xvv.w};
  float ma[4] = {mv.x, mv.y, mv.z, mv.w};
  float m = -1e30f;
#pragma unroll
  for (int j = 0; j < 4; ++j) { xa[j] = clip15(xa[j]) * ma[j]; m = fmaxf(m, xa[j]); }
#pragma unroll
  for (int off = 32; off; off >>= 1) m = fmaxf(m, __shfl_xor(m, off));
  float s = 0.f;
#pragma unroll
  for (int j = 0; j < 4; ++j) { xa[j] = __expf(xa[j] - m) * ma[j]; s += xa[j]; }
#pragma unroll
  for (int off = 32; off; off >>= 1) s += __shfl_xor(s, off);
  float inv = 1.f / (s + 1e-6f);
  *(short4*)(S1 + (size_t)row * LQ + lane * 4) =
      make_short4(f2bf(xa[0] * inv), f2bf(xa[1] * inv), f2bf(xa[2] * inv), f2bf(xa[3] * inv));
}

// A[c,d] = sum_q S1[c,q] Q[q,d]; epilogue writes A_bf and CA_bf = node*A
__global__ void k_gemm_A_mfma(const short* __restrict__ S1, const short* __restrict__ Qbf,
                              const short* __restrict__ node_bf,
                              short* __restrict__ A_bf, short* __restrict__ CA_bf) {
  const int b = blockIdx.x, d0 = blockIdx.y * 64;
  const int tid = threadIdx.x, lane = tid & 63, m0 = (tid >> 6) * 16;
  __shared__ __align__(16) short As[64 * 64];
  __shared__ __align__(16) short Bs[64 * 64];
  f32x4 acc[4] = {};
  const short* S1b = S1 + (size_t)b * KN * LQ;
  const short* Qb = Qbf + (size_t)b * LQ * BH;
  for (int kk = 0; kk < LQ; kk += 64) {
    stage_nat(S1b + kk, LQ, As, tid);
    stage_tr(Qb + (size_t)kk * BH + d0, BH, Bs, tid);
    __syncthreads();
    mfma64(As, Bs, acc, lane, m0);
    __syncthreads();
  }
  const short* nb = node_bf + (size_t)b * KN * BH;
#pragma unroll
  for (int f = 0; f < 4; ++f) {
    int d = d0 + f * 16 + (lane & 15);
#pragma unroll
    for (int e = 0; e < 4; ++e) {
      int c = m0 + (lane >> 4) * 4 + e;
      size_t gi = ((size_t)b * KN + c) * BH + d;
      float av = acc[f][e];
      A_bf[gi] = f2bf(av);
      CA_bf[gi] = f2bf(bf2f(nb[(size_t)c * BH + d]) * av);
    }
  }
}

// T[c,k2] = sum_q S1[c,q] S2[k2,q]
__global__ void k_gemm_T_mfma(const short* __restrict__ S1, const short* __restrict__ S2,
                              short* __restrict__ T) {
  const int b = blockIdx.x;
  const int tid = threadIdx.x, lane = tid & 63, m0 = (tid >> 6) * 16;
  __shared__ __align__(16) short As[64 * 64];
  __shared__ __align__(16) short Bs[64 * 64];
  f32x4 acc[4] = {};
  const short* S1b = S1 + (size_t)b * KN * LQ;
  const short* S2b = S2 + (size_t)b * KN * LQ;
  for (int kk = 0; kk < LQ; kk += 64) {
    stage_nat(S1b + kk, LQ, As, tid);
    stage_nat(S2b + kk, LQ, Bs, tid);
    __syncthreads();
    mfma64(As, Bs, acc, lane, m0);
    __syncthreads();
  }
#pragma unroll
  for (int f = 0; f < 4; ++f) {
    int k2 = f * 16 + (lane & 15);
#pragma unroll
    for (int e = 0; e < 4; ++e) {
      int c = m0 + (lane >> 4) * 4 + e;
      T[((size_t)b * KN + c) * KN + k2] = f2bf(acc[f][e]);
    }
  }
}

// Bm[c,d] = sum_k T[c,k] node[k,d]; writes CB_bf = node*Bm
__global__ void k_gemm_B_mfma(const short* __restrict__ T, const short* __restrict__ node_bf,
                              short* __restrict__ CB_bf) {
  const int b = blockIdx.x, d0 = blockIdx.y * 64;
  const int tid = threadIdx.x, lane = tid & 63, m0 = (tid >> 6) * 16;
  __shared__ __align__(16) short As[64 * 64];
  __shared__ __align__(16) short Bs[64 * 64];
  f32x4 acc[4] = {};
  const short* nb = node_bf + (size_t)b * KN * BH;
  stage_nat(T + (size_t)b * KN * KN, KN, As, tid);
  stage_tr(nb + d0, BH, Bs, tid);
  __syncthreads();
  mfma64(As, Bs, acc, lane, m0);
#pragma unroll
  for (int f = 0; f < 4; ++f) {
    int d = d0 + f * 16 + (lane & 15);
#pragma unroll
    for (int e = 0; e < 4; ++e) {
      int c = m0 + (lane >> 4) * 4 + e;
      CB_bf[((size_t)b * KN + c) * BH + d] = f2bf(bf2f(nb[(size_t)c * BH + d]) * acc[f][e]);
    }
  }
}

// H[c,o] = sum_j feat[c,j]*prjT[o,j]; feat segs {node, A, CA, CB}
__global__ void k_proj_mfma(const short* __restrict__ node_bf, const short* __restrict__ A_bf,
                            const short* __restrict__ CA_bf, const short* __restrict__ CB_bf,
                            const short* __restrict__ prjT, short* __restrict__ H) {
  const int b = blockIdx.x, o0 = blockIdx.y * 64;
  const int tid = threadIdx.x, lane = tid & 63, m0 = (tid >> 6) * 16;
  __shared__ __align__(16) short As[2][64 * 64];
  __shared__ __align__(16) short Bs[2][64 * 64];
  f32x4 acc[4] = {};
  size_t boff = (size_t)b * KN * BH;
  const short* segp[4] = {node_bf + boff, A_bf + boff, CA_bf + boff, CB_bf + boff};
  const short* pT = prjT + (size_t)o0 * 2048;
  for (int kk = 0; kk < 4 * BH; kk += 128) {
#pragma unroll
    for (int h = 0; h < 2; ++h) {
      int k2 = kk + h * 64;
      stage_nat(segp[k2 >> 9] + (k2 & 511), BH, As[h], tid);
      stage_nat(pT + k2, 2048, Bs[h], tid);
    }
    __syncthreads();
    mfma64(As[0], Bs[0], acc, lane, m0);
    mfma64(As[1], Bs[1], acc, lane, m0);
    __syncthreads();
  }
#pragma unroll
  for (int f = 0; f < 4; ++f) {
    int o = o0 + f * 16 + (lane & 15);
#pragma unroll
    for (int e = 0; e < 4; ++e) {
      int c = m0 + (lane >> 4) * 4 + e;
      H[((size_t)b * KN + c) * BH + o] = f2bf(acc[f][e]);
    }
  }
}

// out[b,kb,o] = sum_s x[b,kb,s] W[kb,s,o] + rew[b]*W[kb,1536,o] + bias[kb,o]
// 128b x 128o tile, register-prefetch pipeline: LDS-write(t) -> barrier ->
// issue loads(t+1) -> MFMA(t) -> barrier. Loads of t+1 hide under MFMA(t).
__global__ void k_blk_mfma(const short* __restrict__ Hno, const short* __restrict__ Hna,
                           const short* __restrict__ node_bf, const float* __restrict__ rew,
                           const float* __restrict__ W, const float* __restrict__ bias,
                           float* __restrict__ out) {
  const int bt = blockIdx.x & 1;   // 2 batch tiles
  const int ot = blockIdx.x >> 1;  // 4 out tiles
  const int kb = blockIdx.y;
  const int b0 = bt * 128, o0 = ot * 128;
  const int tid = threadIdx.x, lane = tid & 63, m0 = (tid >> 6) * 32;
  __shared__ __align__(16) short As[128 * 64];
  __shared__ __align__(16) short Bs[128 * 64];  // Bs[n=128][k=64]
  f32x4 acc[16] = {};
  const float* Wk = W + (size_t)kb * SUB_IN * BH;
  const short* segs[3] = {Hno, Hna, node_bf};
  const int kl = (tid & 15) * 4;    // A: k offset (16 thr x 4 elems = 64 k)
  const int ar = tid >> 4;          // A: row base (+it*16 -> 128 rows)
  const int bn0 = (tid & 31) * 4;   // B: n block (32 thr x 4 = 128 n)
  const int bk0 = (tid >> 5) * 8;   // B: k block (8 thr x 8 = 64 k)
  short4 ra[8];
  f32x4 rb[8];

  auto loadA = [&](int kk) {
    const short* src = segs[kk >> 9] + (size_t)kb * BH + (kk & 511) + kl;
#pragma unroll
    for (int it = 0; it < 8; ++it)
      ra[it] = *(const short4*)(src + (size_t)(b0 + ar + it * 16) * (KN * BH));
  };
  auto loadB = [&](int kk) {
#pragma unroll
    for (int j = 0; j < 8; ++j)
      rb[j] = *(const f32x4*)(Wk + (size_t)(kk + bk0 + j) * BH + o0 + bn0);
  };

  loadA(0);
  loadB(0);
  for (int t = 0; t < 24; ++t) {
    // write staged registers to LDS (bf16, swizzled)
#pragma unroll
    for (int it = 0; it < 8; ++it) {
      int row = ar + it * 16;
      *(short4*)((char*)As + SWZ(row, row * 128 + kl * 2)) = ra[it];
    }
#pragma unroll
    for (int j2 = 0; j2 < 4; ++j2) {
      int n = bn0 + j2;
      bf16x8 cv;
#pragma unroll
      for (int j = 0; j < 8; ++j) cv[j] = f2bf(rb[j][j2]);
      *(bf16x8*)((char*)Bs + SWZ(n, n * 128 + bk0 * 2)) = cv;
    }
    __syncthreads();
    if (t < 23) {  // issue next tile's global loads; latency hides under MFMA
      loadA((t + 1) * 64);
      loadB((t + 1) * 64);
    }
#pragma unroll
    for (int kb2 = 0; kb2 < 2; ++kb2) {
      int k16 = kb2 * 32 + (lane >> 4) * 8;
#pragma unroll
      for (int mi = 0; mi < 2; ++mi) {
        int arow = m0 + mi * 16 + (lane & 15);
        bf16x8 af = *(const bf16x8*)((const char*)As + SWZ(arow, arow * 128 + k16 * 2));
#pragma unroll
        for (int f = 0; f < 8; ++f) {
          int nrow = f * 16 + (lane & 15);
          bf16x8 bfr = *(const bf16x8*)((const char*)Bs + SWZ(nrow, nrow * 128 + k16 * 2));
          acc[mi * 8 + f] = __builtin_amdgcn_mfma_f32_16x16x32_bf16(af, bfr, acc[mi * 8 + f], 0, 0, 0);
        }
      }
    }
    __syncthreads();
  }
#pragma unroll
  for (int mi = 0; mi < 2; ++mi) {
#pragma unroll
    for (int f = 0; f < 8; ++f) {
      int o = o0 + f * 16 + (lane & 15);
      float wr = Wk[(size_t)1536 * BH + o];
      float bv = bias[kb * BH + o];
#pragma unroll
      for (int e = 0; e < 4; ++e) {
        int bb = b0 + m0 + mi * 16 + (lane >> 4) * 4 + e;
        out[((size_t)bb * KN + kb) * BH + o] = acc[mi * 8 + f][e] + rew[bb] * wr + bv;
      }
    }
  }
}

extern "C" void kernel_launch(void* const* d_in, const int* in_sizes, int n_in,
                              void* d_out, int out_size, void* d_ws, size_t ws_size,
                              hipStream_t stream) {
  (void)in_sizes; (void)n_in; (void)out_size; (void)ws_size;
  const float* act   = (const float*)d_in[0];
  const float* obs   = (const float*)d_in[1];
  const float* amask = (const float*)d_in[2];
  const float* omask = (const float*)d_in[3];
  const float* rew   = (const float*)d_in[4];
  const float* node  = (const float*)d_in[5];
  const float* nmask = (const float*)d_in[6];
  const float* w4C_o = (const float*)d_in[7];
  const float* w4Q_o = (const float*)d_in[8];
  const float* w4m_o = (const float*)d_in[9];
  const float* bias_o= (const float*)d_in[10];
  const float* w4C_a = (const float*)d_in[11];
  const float* w4Q_a = (const float*)d_in[12];
  const float* w4m_a = (const float*)d_in[13];
  const float* bias_a= (const float*)d_in[14];
  const float* prj_o = (const float*)d_in[15];
  const float* prj_a = (const float*)d_in[16];
  const float* blkW  = (const float*)d_in[17];
  const float* blkb  = (const float*)d_in[18];
  float* out = (float*)d_out;

  char* wsb = (char*)d_ws;
  auto alloc = [&](size_t bytes) { char* p = wsb; wsb += (bytes + 255) & ~255ull; return p; };
  const size_t NKB = (size_t)BS * KN * BH;   // 8.4M elems
  const size_t NQB = (size_t)BS * LQ * BH;   // 33.6M elems
  short* node_bf = (short*)alloc(NKB * 2);
  short* CwCA    = (short*)alloc(NKB * 2);   // Cw during score; CA after gemm_A
  short* prjT    = (short*)alloc((size_t)2048 * BH * 2);
  short* Q_bf    = (short*)alloc(NQB * 2);
  float* S       = (float*)alloc((size_t)BS * KN * LQ * 4);  // aliased as CB after softmax_q
  short* CB      = (short*)S;
  short* S1      = (short*)alloc((size_t)BS * KN * LQ * 2);
  short* S2      = (short*)alloc((size_t)BS * KN * LQ * 2);
  short* A_bf    = (short*)alloc(NKB * 2);
  short* T_bf    = (short*)alloc((size_t)BS * KN * KN * 2);
  short* Hno     = (short*)alloc(NKB * 2);
  short* Hna     = (short*)alloc(NKB * 2);
  float* cw      = (float*)alloc((size_t)BS * KN * 4);
  float* qw      = (float*)alloc((size_t)BS * LQ * 4);

  k_cvt<<<dim3((int)(NKB / 4 / 256)), 256, 0, stream>>>(node, node_bf, (int)(NKB / 4));

  for (int head = 0; head < 2; ++head) {
    const float* Qseq  = head ? act : obs;
    const float* qmask = head ? amask : omask;
    const float* w4C   = head ? w4C_a : w4C_o;
    const float* w4Q   = head ? w4Q_a : w4Q_o;
    const float* w4m   = head ? w4m_a : w4m_o;
    const float* bias  = head ? bias_a : bias_o;
    const float* prj   = head ? prj_a : prj_o;
    short* H = head ? Hna : Hno;

    k_cvt<<<dim3((int)(NQB / 4 / 256)), 256, 0, stream>>>(Qseq, Q_bf, (int)(NQB / 4));
    k_cvt_scaled<<<dim3((int)(NKB / 4 / 256)), 256, 0, stream>>>(node, w4m, CwCA, (int)(NKB / 4));
    k_prjT<<<dim3(64, 16), 256, 0, stream>>>(prj, prjT);
    k_rowdot<<<dim3(BS * KN / 4), 256, 0, stream>>>(node, w4C, cw, BS * KN);
    k_rowdot<<<dim3(BS * LQ / 4), 256, 0, stream>>>(Qseq, w4Q, qw, BS * LQ);
    k_score_mfma<<<dim3(BS, LQ / 64), 256, 0, stream>>>(CwCA, Q_bf, cw, qw, bias, nmask, S, S2);
    k_softmax_q<<<dim3(BS * KN / 4), 256, 0, stream>>>(S, qmask, S1);
    k_gemm_A_mfma<<<dim3(BS, BH / 64), 256, 0, stream>>>(S1, Q_bf, node_bf, A_bf, CwCA);
    k_gemm_T_mfma<<<dim3(BS), 256, 0, stream>>>(S1, S2, T_bf);
    k_gemm_B_mfma<<<dim3(BS, BH / 64), 256, 0, stream>>>(T_bf, node_bf, CB);
    k_proj_mfma<<<dim3(BS, BH / 64), 256, 0, stream>>>(node_bf, A_bf, CwCA, CB, prjT, H);
  }
  k_blk_mfma<<<dim3(8, KN), 256, 0, stream>>>(Hno, Hna, node_bf, rew, blkW, blkb, out);
}

// Round 5
// 692.082 us; speedup vs baseline: 1.0104x; 1.0104x over previous
//
#include <hip/hip_runtime.h>
#include <math.h>

#define BS 256
#define LQ 256
#define KN 64
#define BH 512
#define SUB_IN 1537

typedef __attribute__((ext_vector_type(8))) short bf16x8;
typedef __attribute__((ext_vector_type(4))) float f32x4;

__device__ __forceinline__ float clip15(float x) {
  return fminf(fmaxf(x, -15.f), 15.f);
}
__device__ __forceinline__ short f2bf(float f) {
  unsigned u = __float_as_uint(f);
  u = u + 0x7fffu + ((u >> 16) & 1u);
  return (short)(u >> 16);
}
__device__ __forceinline__ float bf2f(short s) {
  return __uint_as_float(((unsigned)(unsigned short)s) << 16);
}

// XOR swizzle on the 16B slot within each 128B LDS row (proven R2-R4)
#define SWZ(row, byte) ((byte) ^ (((((row) ^ ((row) >> 3)) & 7)) << 4))

// async global->LDS, 16B per lane; LDS dest = wave-uniform base + lane*16
__device__ __forceinline__ void gl_lds16(const short* g, short* l) {
  __builtin_amdgcn_global_load_lds(
      (const __attribute__((address_space(1))) void*)g,
      (__attribute__((address_space(3))) void*)l, 16, 0, 0);
}

// ---------------- prep kernels ----------------

// per row: bf16 convert + row-dot with w (fused rowdot)
__global__ void k_cvtQ_fused(const float* __restrict__ X, const float* __restrict__ w,
                             short* __restrict__ Xbf, float* __restrict__ rd) {
  int row = blockIdx.x * 4 + (threadIdx.x >> 6);
  int lane = threadIdx.x & 63;
  const float* x = X + (size_t)row * BH + lane * 8;
  f32x4 v0 = *(const f32x4*)x;
  f32x4 v1 = *(const f32x4*)(x + 4);
  f32x4 w0 = *(const f32x4*)(w + lane * 8);
  f32x4 w1 = *(const f32x4*)(w + lane * 8 + 4);
  float s = v0[0] * w0[0] + v0[1] * w0[1] + v0[2] * w0[2] + v0[3] * w0[3] +
            v1[0] * w1[0] + v1[1] * w1[1] + v1[2] * w1[2] + v1[3] * w1[3];
#pragma unroll
  for (int off = 32; off; off >>= 1) s += __shfl_down(s, off);
  if (lane == 0) rd[row] = s;
  bf16x8 o;
#pragma unroll
  for (int j = 0; j < 4; ++j) { o[j] = f2bf(v0[j]); o[4 + j] = f2bf(v1[j]); }
  *(bf16x8*)(Xbf + (size_t)row * BH + lane * 8) = o;
}

// per node row: rowdot with w4C -> cw; CwCA = bf16(node*w4m); optional node_bf
__global__ void k_cvtC_fused(const float* __restrict__ X, const float* __restrict__ wc,
                             const float* __restrict__ wm, short* __restrict__ Xbf,
                             short* __restrict__ Xw, float* __restrict__ rd, int writeXbf) {
  int row = blockIdx.x * 4 + (threadIdx.x >> 6);
  int lane = threadIdx.x & 63;
  const float* x = X + (size_t)row * BH + lane * 8;
  f32x4 v0 = *(const f32x4*)x;
  f32x4 v1 = *(const f32x4*)(x + 4);
  f32x4 c0 = *(const f32x4*)(wc + lane * 8);
  f32x4 c1 = *(const f32x4*)(wc + lane * 8 + 4);
  f32x4 m0 = *(const f32x4*)(wm + lane * 8);
  f32x4 m1 = *(const f32x4*)(wm + lane * 8 + 4);
  float s = v0[0] * c0[0] + v0[1] * c0[1] + v0[2] * c0[2] + v0[3] * c0[3] +
            v1[0] * c1[0] + v1[1] * c1[1] + v1[2] * c1[2] + v1[3] * c1[3];
#pragma unroll
  for (int off = 32; off; off >>= 1) s += __shfl_down(s, off);
  if (lane == 0) rd[row] = s;
  bf16x8 ow;
#pragma unroll
  for (int j = 0; j < 4; ++j) { ow[j] = f2bf(v0[j] * m0[j]); ow[4 + j] = f2bf(v1[j] * m1[j]); }
  *(bf16x8*)(Xw + (size_t)row * BH + lane * 8) = ow;
  if (writeXbf) {
    bf16x8 ob;
#pragma unroll
    for (int j = 0; j < 4; ++j) { ob[j] = f2bf(v0[j]); ob[4 + j] = f2bf(v1[j]); }
    *(bf16x8*)(Xbf + (size_t)row * BH + lane * 8) = ob;
  }
}

// prjT[n][k] = bf16(prj[k][n]); k=2048, n=512
__global__ void k_prjT(const float* __restrict__ prj, short* __restrict__ prjT) {
  __shared__ float t[32][33];
  int k0 = blockIdx.x * 32, n0 = blockIdx.y * 32;
  int x = threadIdx.x & 31, y = threadIdx.x >> 5;  // 32x8
  for (int yy = y; yy < 32; yy += 8)
    t[yy][x] = prj[(size_t)(k0 + yy) * BH + n0 + x];
  __syncthreads();
  for (int yy = y; yy < 32; yy += 8)
    prjT[(size_t)(n0 + yy) * 2048 + k0 + x] = f2bf(t[x][yy]);
}

// WT[kb][o][s] = bf16(W[kb][s][o]); s<1536 only (reward row handled in epilogue)
__global__ void k_WT(const float* __restrict__ W, short* __restrict__ WT) {
  __shared__ float t[32][33];
  int s0 = blockIdx.x * 32, o0 = blockIdx.y * 32, kb = blockIdx.z;
  const float* Wk = W + (size_t)kb * SUB_IN * BH;
  int x = threadIdx.x & 31, y = threadIdx.x >> 5;
  for (int yy = y; yy < 32; yy += 8)
    t[yy][x] = Wk[(size_t)(s0 + yy) * BH + o0 + x];
  __syncthreads();
  for (int yy = y; yy < 32; yy += 8)
    WT[((size_t)kb * BH + o0 + yy) * 1536 + s0 + x] = f2bf(t[x][yy]);
}

// ---------------- staging helpers (64x64 bf16 tile into SWZ'd LDS) ----------------

__device__ __forceinline__ void stage_nat(const short* __restrict__ src, size_t ld,
                                          short* As, int tid) {
  int kl = (tid & 15) * 4;
#pragma unroll
  for (int it = 0; it < 4; ++it) {
    int row = (tid >> 4) + it * 16;
    short4 v = *(const short4*)(src + (size_t)row * ld + kl);
    *(short4*)((char*)As + SWZ(row, row * 128 + kl * 2)) = v;
  }
}

// transposed: bf16 source [k][n] (stride ld) -> Bs[n][k]
__device__ __forceinline__ void stage_tr(const short* __restrict__ src, size_t ld,
                                         short* Bs, int tid) {
  int n0 = (tid & 15) * 4;
  int k0 = (tid >> 4) * 4;
  short4 r0 = *(const short4*)(src + (size_t)(k0 + 0) * ld + n0);
  short4 r1 = *(const short4*)(src + (size_t)(k0 + 1) * ld + n0);
  short4 r2 = *(const short4*)(src + (size_t)(k0 + 2) * ld + n0);
  short4 r3 = *(const short4*)(src + (size_t)(k0 + 3) * ld + n0);
  *(short4*)((char*)Bs + SWZ(n0 + 0, (n0 + 0) * 128 + k0 * 2)) = make_short4(r0.x, r1.x, r2.x, r3.x);
  *(short4*)((char*)Bs + SWZ(n0 + 1, (n0 + 1) * 128 + k0 * 2)) = make_short4(r0.y, r1.y, r2.y, r3.y);
  *(short4*)((char*)Bs + SWZ(n0 + 2, (n0 + 2) * 128 + k0 * 2)) = make_short4(r0.z, r1.z, r2.z, r3.z);
  *(short4*)((char*)Bs + SWZ(n0 + 3, (n0 + 3) * 128 + k0 * 2)) = make_short4(r0.w, r1.w, r2.w, r3.w);
}

// wave computes 16 rows (m0..m0+15) x 64 cols of a 64x64 tile
__device__ __forceinline__ void mfma64(const short* As, const short* Bs,
                                       f32x4 acc[4], int lane, int m0) {
#pragma unroll
  for (int kb = 0; kb < 2; ++kb) {
    int k16 = kb * 32 + (lane >> 4) * 8;
    int arow = m0 + (lane & 15);
    bf16x8 af = *(const bf16x8*)((const char*)As + SWZ(arow, arow * 128 + k16 * 2));
#pragma unroll
    for (int f = 0; f < 4; ++f) {
      int nrow = f * 16 + (lane & 15);
      bf16x8 bfr = *(const bf16x8*)((const char*)Bs + SWZ(nrow, nrow * 128 + k16 * 2));
      acc[f] = __builtin_amdgcn_mfma_f32_16x16x32_bf16(af, bfr, acc[f], 0, 0, 0);
    }
  }
}

// ---------------- MFMA pipeline kernels ----------------

// S[b,c,q] = sum_d Cw[c,d]*Q[q,d] + cw[c] + qw[q] + bias
// Fused epilogue: S2 = masked_softmax over c (cmask), written as bf16.
__global__ void k_score_mfma(const short* __restrict__ Cw, const short* __restrict__ Qbf,
                             const float* __restrict__ cw, const float* __restrict__ qw,
                             const float* __restrict__ bias, const float* __restrict__ cmask,
                             float* __restrict__ S, short* __restrict__ S2) {
  const int b = blockIdx.x, q0 = blockIdx.y * 64;
  const int tid = threadIdx.x, lane = tid & 63, wave = tid >> 6, m0 = wave * 16;
  __shared__ __align__(16) short As[2][64 * 64];
  __shared__ __align__(16) short Bs[2][64 * 64];
  f32x4 acc[4] = {};
  const short* Cb = Cw + (size_t)b * KN * BH;
  const short* Qb = Qbf + ((size_t)b * LQ + q0) * BH;
  for (int kk = 0; kk < BH; kk += 128) {
    stage_nat(Cb + kk, BH, As[0], tid);
    stage_nat(Cb + kk + 64, BH, As[1], tid);
    stage_nat(Qb + kk, BH, Bs[0], tid);
    stage_nat(Qb + kk + 64, BH, Bs[1], tid);
    __syncthreads();
    mfma64(As[0], Bs[0], acc, lane, m0);
    mfma64(As[1], Bs[1], acc, lane, m0);
    __syncthreads();
  }
  const float bv = bias[0];
  const int l15 = lane & 15, g4 = lane >> 4;
  float sraw[4][4], xv[4][4], cmv[4], cwv[4];
#pragma unroll
  for (int e = 0; e < 4; ++e) {
    int c = m0 + g4 * 4 + e;
    cmv[e] = cmask[b * KN + c];
    cwv[e] = cw[b * KN + c];
  }
#pragma unroll
  for (int f = 0; f < 4; ++f) {
    int q = q0 + f * 16 + l15;
    float qv = qw[b * LQ + q] + bv;
#pragma unroll
    for (int e = 0; e < 4; ++e) {
      sraw[f][e] = acc[f][e] + cwv[e] + qv;
      xv[f][e] = clip15(sraw[f][e]) * cmv[e];
    }
  }
  float* red = (float*)As;  // reuse LDS
  float wm[4];
#pragma unroll
  for (int f = 0; f < 4; ++f) {
    float m = fmaxf(fmaxf(xv[f][0], xv[f][1]), fmaxf(xv[f][2], xv[f][3]));
    m = fmaxf(m, __shfl_xor(m, 16));
    m = fmaxf(m, __shfl_xor(m, 32));
    wm[f] = m;
  }
  if (g4 == 0) {
#pragma unroll
    for (int f = 0; f < 4; ++f) red[(wave * 4 + f) * 16 + l15] = wm[f];
  }
  __syncthreads();
  float cmax[4];
#pragma unroll
  for (int f = 0; f < 4; ++f) {
    float m = red[f * 16 + l15];
#pragma unroll
    for (int w2 = 1; w2 < 4; ++w2) m = fmaxf(m, red[(w2 * 4 + f) * 16 + l15]);
    cmax[f] = m;
  }
  __syncthreads();
  float wsum[4];
#pragma unroll
  for (int f = 0; f < 4; ++f) {
    float s = 0.f;
#pragma unroll
    for (int e = 0; e < 4; ++e) s += __expf(xv[f][e] - cmax[f]) * cmv[e];
    s += __shfl_xor(s, 16);
    s += __shfl_xor(s, 32);
    wsum[f] = s;
  }
  if (g4 == 0) {
#pragma unroll
    for (int f = 0; f < 4; ++f) red[(wave * 4 + f) * 16 + l15] = wsum[f];
  }
  __syncthreads();
#pragma unroll
  for (int f = 0; f < 4; ++f) {
    float s = 0.f;
#pragma unroll
    for (int w2 = 0; w2 < 4; ++w2) s += red[(w2 * 4 + f) * 16 + l15];
    float inv = 1.f / (s + 1e-6f);
    int q = q0 + f * 16 + l15;
#pragma unroll
    for (int e = 0; e < 4; ++e) {
      int c = m0 + g4 * 4 + e;
      S[((size_t)b * KN + c) * LQ + q] = sraw[f][e];
      S2[((size_t)b * KN + c) * LQ + q] = f2bf(__expf(xv[f][e] - cmax[f]) * cmv[e] * inv);
    }
  }
}

__global__ void k_softmax_q(const float* __restrict__ S, const float* __restrict__ qmask,
                            short* __restrict__ S1) {
  int row = blockIdx.x * 4 + (threadIdx.x >> 6);
  int lane = threadIdx.x & 63;
  int b = row >> 6;
  const float4* Sr = (const float4*)(S + (size_t)row * LQ);
  const float4* Qm = (const float4*)(qmask + (size_t)b * LQ);
  float4 xvv = Sr[lane];
  float4 mv = Qm[lane];
  float xa[4] = {xvv.x, xvv.y, xvv.z, xvv.w};
  float ma[4] = {mv.x, mv.y, mv.z, mv.w};
  float m = -1e30f;
#pragma unroll
  for (int j = 0; j < 4; ++j) { xa[j] = clip15(xa[j]) * ma[j]; m = fmaxf(m, xa[j]); }
#pragma unroll
  for (int off = 32; off; off >>= 1) m = fmaxf(m, __shfl_xor(m, off));
  float s = 0.f;
#pragma unroll
  for (int j = 0; j < 4; ++j) { xa[j] = __expf(xa[j] - m) * ma[j]; s += xa[j]; }
#pragma unroll
  for (int off = 32; off; off >>= 1) s += __shfl_xor(s, off);
  float inv = 1.f / (s + 1e-6f);
  *(short4*)(S1 + (size_t)row * LQ + lane * 4) =
      make_short4(f2bf(xa[0] * inv), f2bf(xa[1] * inv), f2bf(xa[2] * inv), f2bf(xa[3] * inv));
}

// A[c,d] = sum_q S1[c,q] Q[q,d]; epilogue writes A_bf and CA_bf = node*A
__global__ void k_gemm_A_mfma(const short* __restrict__ S1, const short* __restrict__ Qbf,
                              const short* __restrict__ node_bf,
                              short* __restrict__ A_bf, short* __restrict__ CA_bf) {
  const int b = blockIdx.x, d0 = blockIdx.y * 64;
  const int tid = threadIdx.x, lane = tid & 63, m0 = (tid >> 6) * 16;
  __shared__ __align__(16) short As[64 * 64];
  __shared__ __align__(16) short Bs[64 * 64];
  f32x4 acc[4] = {};
  const short* S1b = S1 + (size_t)b * KN * LQ;
  const short* Qb = Qbf + (size_t)b * LQ * BH;
  for (int kk = 0; kk < LQ; kk += 64) {
    stage_nat(S1b + kk, LQ, As, tid);
    stage_tr(Qb + (size_t)kk * BH + d0, BH, Bs, tid);
    __syncthreads();
    mfma64(As, Bs, acc, lane, m0);
    __syncthreads();
  }
  const short* nb = node_bf + (size_t)b * KN * BH;
#pragma unroll
  for (int f = 0; f < 4; ++f) {
    int d = d0 + f * 16 + (lane & 15);
#pragma unroll
    for (int e = 0; e < 4; ++e) {
      int c = m0 + (lane >> 4) * 4 + e;
      size_t gi = ((size_t)b * KN + c) * BH + d;
      float av = acc[f][e];
      A_bf[gi] = f2bf(av);
      CA_bf[gi] = f2bf(bf2f(nb[(size_t)c * BH + d]) * av);
    }
  }
}

// T[c,k2] = sum_q S1[c,q] S2[k2,q]
__global__ void k_gemm_T_mfma(const short* __restrict__ S1, const short* __restrict__ S2,
                              short* __restrict__ T) {
  const int b = blockIdx.x;
  const int tid = threadIdx.x, lane = tid & 63, m0 = (tid >> 6) * 16;
  __shared__ __align__(16) short As[64 * 64];
  __shared__ __align__(16) short Bs[64 * 64];
  f32x4 acc[4] = {};
  const short* S1b = S1 + (size_t)b * KN * LQ;
  const short* S2b = S2 + (size_t)b * KN * LQ;
  for (int kk = 0; kk < LQ; kk += 64) {
    stage_nat(S1b + kk, LQ, As, tid);
    stage_nat(S2b + kk, LQ, Bs, tid);
    __syncthreads();
    mfma64(As, Bs, acc, lane, m0);
    __syncthreads();
  }
#pragma unroll
  for (int f = 0; f < 4; ++f) {
    int k2 = f * 16 + (lane & 15);
#pragma unroll
    for (int e = 0; e < 4; ++e) {
      int c = m0 + (lane >> 4) * 4 + e;
      T[((size_t)b * KN + c) * KN + k2] = f2bf(acc[f][e]);
    }
  }
}

// Bm[c,d] = sum_k T[c,k] node[k,d]; writes CB_bf = node*Bm
__global__ void k_gemm_B_mfma(const short* __restrict__ T, const short* __restrict__ node_bf,
                              short* __restrict__ CB_bf) {
  const int b = blockIdx.x, d0 = blockIdx.y * 64;
  const int tid = threadIdx.x, lane = tid & 63, m0 = (tid >> 6) * 16;
  __shared__ __align__(16) short As[64 * 64];
  __shared__ __align__(16) short Bs[64 * 64];
  f32x4 acc[4] = {};
  const short* nb = node_bf + (size_t)b * KN * BH;
  stage_nat(T + (size_t)b * KN * KN, KN, As, tid);
  stage_tr(nb + d0, BH, Bs, tid);
  __syncthreads();
  mfma64(As, Bs, acc, lane, m0);
#pragma unroll
  for (int f = 0; f < 4; ++f) {
    int d = d0 + f * 16 + (lane & 15);
#pragma unroll
    for (int e = 0; e < 4; ++e) {
      int c = m0 + (lane >> 4) * 4 + e;
      CB_bf[((size_t)b * KN + c) * BH + d] = f2bf(bf2f(nb[(size_t)c * BH + d]) * acc[f][e]);
    }
  }
}

// H[c,o] = sum_j feat[c,j]*prjT[o,j]; feat segs {node, A, CA, CB}
__global__ void k_proj_mfma(const short* __restrict__ node_bf, const short* __restrict__ A_bf,
                            const short* __restrict__ CA_bf, const short* __restrict__ CB_bf,
                            const short* __restrict__ prjT, short* __restrict__ H) {
  const int b = blockIdx.x, o0 = blockIdx.y * 64;
  const int tid = threadIdx.x, lane = tid & 63, m0 = (tid >> 6) * 16;
  __shared__ __align__(16) short As[2][64 * 64];
  __shared__ __align__(16) short Bs[2][64 * 64];
  f32x4 acc[4] = {};
  size_t boff = (size_t)b * KN * BH;
  const short* segp[4] = {node_bf + boff, A_bf + boff, CA_bf + boff, CB_bf + boff};
  const short* pT = prjT + (size_t)o0 * 2048;
  for (int kk = 0; kk < 4 * BH; kk += 128) {
#pragma unroll
    for (int h = 0; h < 2; ++h) {
      int k2 = kk + h * 64;
      stage_nat(segp[k2 >> 9] + (k2 & 511), BH, As[h], tid);
      stage_nat(pT + k2, 2048, Bs[h], tid);
    }
    __syncthreads();
    mfma64(As[0], Bs[0], acc, lane, m0);
    mfma64(As[1], Bs[1], acc, lane, m0);
    __syncthreads();
  }
#pragma unroll
  for (int f = 0; f < 4; ++f) {
    int o = o0 + f * 16 + (lane & 15);
#pragma unroll
    for (int e = 0; e < 4; ++e) {
      int c = m0 + (lane >> 4) * 4 + e;
      H[((size_t)b * KN + c) * BH + o] = f2bf(acc[f][e]);
    }
  }
}

// out[b,kb,o] = sum_s x[b,kb,s] WT[kb,o,s] + rew[b]*W[kb,1536,o] + bias[kb,o]
// global_load_lds double-buffered 2-phase pipeline; one barrier per K-step.
// LDS linear, source pre-swizzled, reads SWZ'd (both-sides rule).
__global__ void k_blk_mfma(const short* __restrict__ Hno, const short* __restrict__ Hna,
                           const short* __restrict__ node_bf, const float* __restrict__ rew,
                           const short* __restrict__ WT, const float* __restrict__ W,
                           const float* __restrict__ bias, float* __restrict__ out) {
  const int bt = blockIdx.x & 1;   // 2 batch tiles
  const int ot = blockIdx.x >> 1;  // 4 out tiles
  const int kb = blockIdx.y;
  const int b0 = bt * 128, o0 = ot * 128;
  const int tid = threadIdx.x, lane = tid & 63, wave = tid >> 6, m0 = wave * 32;
  __shared__ __align__(16) short As[2][128 * 64];
  __shared__ __align__(16) short Bs[2][128 * 64];
  f32x4 acc[16] = {};
  const short* segs[3] = {Hno, Hna, node_bf};
  const int wh = wave & 1;  // half of the operand this wave stages
  const int lr = lane >> 3; // row-within-call
  const int ls = lane & 7;  // 16B slot-within-row

  // waves 0,1 stage A (128 batch-rows x 64 k); waves 2,3 stage B (128 o-rows x 64 s)
  auto STAGE = [&](int kk, int buf) {
    if (wave < 2) {
      const short* base = segs[kk >> 9] + (size_t)kb * BH + (kk & 511);
#pragma unroll
      for (int c = 0; c < 8; ++c) {
        int row = wh * 64 + c * 8 + lr;
        int sw = ls ^ ((row ^ (row >> 3)) & 7);
        gl_lds16(base + (size_t)(b0 + row) * (KN * BH) + sw * 8,
                 As[buf] + wh * 4096 + c * 512);
      }
    } else {
      const short* base = WT + ((size_t)kb * BH + o0) * 1536 + kk;
#pragma unroll
      for (int c = 0; c < 8; ++c) {
        int row = wh * 64 + c * 8 + lr;
        int sw = ls ^ ((row ^ (row >> 3)) & 7);
        gl_lds16(base + (size_t)row * 1536 + sw * 8,
                 Bs[buf] + wh * 4096 + c * 512);
      }
    }
  };

  STAGE(0, 0);
  __syncthreads();
  int cur = 0;
  for (int t = 0; t < 24; ++t) {
    if (t < 23) STAGE((t + 1) * 64, cur ^ 1);  // async loads overlap MFMA below
    const short* Ac = As[cur];
    const short* Bc = Bs[cur];
#pragma unroll
    for (int kb2 = 0; kb2 < 2; ++kb2) {
      int k16 = kb2 * 32 + (lane >> 4) * 8;
#pragma unroll
      for (int mi = 0; mi < 2; ++mi) {
        int arow = m0 + mi * 16 + (lane & 15);
        bf16x8 af = *(const bf16x8*)((const char*)Ac + SWZ(arow, arow * 128 + k16 * 2));
#pragma unroll
        for (int f = 0; f < 8; ++f) {
          int nrow = f * 16 + (lane & 15);
          bf16x8 bfr = *(const bf16x8*)((const char*)Bc + SWZ(nrow, nrow * 128 + k16 * 2));
          acc[mi * 8 + f] = __builtin_amdgcn_mfma_f32_16x16x32_bf16(af, bfr, acc[mi * 8 + f], 0, 0, 0);
        }
      }
    }
    __syncthreads();  // drains vmcnt: next buffer ready
    cur ^= 1;
  }
  const float* Wk = W + (size_t)kb * SUB_IN * BH;
#pragma unroll
  for (int mi = 0; mi < 2; ++mi) {
#pragma unroll
    for (int f = 0; f < 8; ++f) {
      int o = o0 + f * 16 + (lane & 15);
      float wr = Wk[(size_t)1536 * BH + o];
      float bv = bias[kb * BH + o];
#pragma unroll
      for (int e = 0; e < 4; ++e) {
        int bb = b0 + m0 + mi * 16 + (lane >> 4) * 4 + e;
        out[((size_t)bb * KN + kb) * BH + o] = acc[mi * 8 + f][e] + rew[bb] * wr + bv;
      }
    }
  }
}

extern "C" void kernel_launch(void* const* d_in, const int* in_sizes, int n_in,
                              void* d_out, int out_size, void* d_ws, size_t ws_size,
                              hipStream_t stream) {
  (void)in_sizes; (void)n_in; (void)out_size; (void)ws_size;
  const float* act   = (const float*)d_in[0];
  const float* obs   = (const float*)d_in[1];
  const float* amask = (const float*)d_in[2];
  const float* omask = (const float*)d_in[3];
  const float* rew   = (const float*)d_in[4];
  const float* node  = (const float*)d_in[5];
  const float* nmask = (const float*)d_in[6];
  const float* w4C_o = (const float*)d_in[7];
  const float* w4Q_o = (const float*)d_in[8];
  const float* w4m_o = (const float*)d_in[9];
  const float* bias_o= (const float*)d_in[10];
  const float* w4C_a = (const float*)d_in[11];
  const float* w4Q_a = (const float*)d_in[12];
  const float* w4m_a = (const float*)d_in[13];
  const float* bias_a= (const float*)d_in[14];
  const float* prj_o = (const float*)d_in[15];
  const float* prj_a = (const float*)d_in[16];
  const float* blkW  = (const float*)d_in[17];
  const float* blkb  = (const float*)d_in[18];
  float* out = (float*)d_out;

  char* wsb = (char*)d_ws;
  auto alloc = [&](size_t bytes) { char* p = wsb; wsb += (bytes + 255) & ~255ull; return p; };
  const size_t NKB = (size_t)BS * KN * BH;   // 8.4M elems
  const size_t NQB = (size_t)BS * LQ * BH;   // 33.6M elems
  short* node_bf = (short*)alloc(NKB * 2);
  short* CwCA    = (short*)alloc(NKB * 2);   // Cw during score; CA after gemm_A
  short* prjT    = (short*)alloc((size_t)2048 * BH * 2);
  short* Q_bf    = (short*)alloc(NQB * 2);   // also start of WT (after both heads done)
  float* S       = (float*)alloc((size_t)BS * KN * LQ * 4);  // CB after softmax; tail of WT
  short* CB      = (short*)S;
  short* WT      = (short*)Q_bf;             // [64][512][1536] bf16 = 100.6 MB over Q_bf+S
  short* S1      = (short*)alloc((size_t)BS * KN * LQ * 2);
  short* S2      = (short*)alloc((size_t)BS * KN * LQ * 2);
  short* A_bf    = (short*)alloc(NKB * 2);
  short* T_bf    = (short*)alloc((size_t)BS * KN * KN * 2);
  short* Hno     = (short*)alloc(NKB * 2);
  short* Hna     = (short*)alloc(NKB * 2);
  float* cw      = (float*)alloc((size_t)BS * KN * 4);
  float* qw      = (float*)alloc((size_t)BS * LQ * 4);

  for (int head = 0; head < 2; ++head) {
    const float* Qseq  = head ? act : obs;
    const float* qmask = head ? amask : omask;
    const float* w4C   = head ? w4C_a : w4C_o;
    const float* w4Q   = head ? w4Q_a : w4Q_o;
    const float* w4m   = head ? w4m_a : w4m_o;
    const float* bias  = head ? bias_a : bias_o;
    const float* prj   = head ? prj_a : prj_o;
    short* H = head ? Hna : Hno;

    k_cvtQ_fused<<<dim3(BS * LQ / 4), 256, 0, stream>>>(Qseq, w4Q, Q_bf, qw);
    k_cvtC_fused<<<dim3(BS * KN / 4), 256, 0, stream>>>(node, w4C, w4m, node_bf, CwCA, cw,
                                                        head == 0 ? 1 : 0);
    k_prjT<<<dim3(64, 16), 256, 0, stream>>>(prj, prjT);
    k_score_mfma<<<dim3(BS, LQ / 64), 256, 0, stream>>>(CwCA, Q_bf, cw, qw, bias, nmask, S, S2);
    k_softmax_q<<<dim3(BS * KN / 4), 256, 0, stream>>>(S, qmask, S1);
    k_gemm_A_mfma<<<dim3(BS, BH / 64), 256, 0, stream>>>(S1, Q_bf, node_bf, A_bf, CwCA);
    k_gemm_T_mfma<<<dim3(BS), 256, 0, stream>>>(S1, S2, T_bf);
    k_gemm_B_mfma<<<dim3(BS, BH / 64), 256, 0, stream>>>(T_bf, node_bf, CB);
    k_proj_mfma<<<dim3(BS, BH / 64), 256, 0, stream>>>(node_bf, A_bf, CwCA, CB, prjT, H);
  }
  // W transpose+convert into workspace (Q_bf/S regions are dead now)
  k_WT<<<dim3(48, 16, 64), 256, 0, stream>>>(blkW, WT);
  k_blk_mfma<<<dim3(8, KN), 256, 0, stream>>>(Hno, Hna, node_bf, rew, WT, blkW, blkb, out);
}

// Round 7
// 687.684 us; speedup vs baseline: 1.0169x; 1.0064x over previous
//
#include <hip/hip_runtime.h>
#include <math.h>

#define BS 256
#define LQ 256
#define KN 64
#define BH 512
#define SUB_IN 1537

typedef __attribute__((ext_vector_type(8))) short bf16x8;
typedef __attribute__((ext_vector_type(4))) float f32x4;

__device__ __forceinline__ float clip15(float x) {
  return fminf(fmaxf(x, -15.f), 15.f);
}
__device__ __forceinline__ short f2bf(float f) {
  unsigned u = __float_as_uint(f);
  u = u + 0x7fffu + ((u >> 16) & 1u);
  return (short)(u >> 16);
}
__device__ __forceinline__ float bf2f(short s) {
  return __uint_as_float(((unsigned)(unsigned short)s) << 16);
}

// XOR swizzle on the 16B slot within each 128B LDS row (proven R2-R5)
#define SWZ(row, byte) ((byte) ^ (((((row) ^ ((row) >> 3)) & 7)) << 4))

// async global->LDS, 16B per lane; LDS dest = wave-uniform base + lane*16
__device__ __forceinline__ void gl_lds16(const short* g, short* l) {
  __builtin_amdgcn_global_load_lds(
      (const __attribute__((address_space(1))) void*)g,
      (__attribute__((address_space(3))) void*)l, 16, 0, 0);
}

// ---------------- prep kernels ----------------

__global__ void k_cvtQ_fused(const float* __restrict__ X, const float* __restrict__ w,
                             short* __restrict__ Xbf, float* __restrict__ rd) {
  int row = blockIdx.x * 4 + (threadIdx.x >> 6);
  int lane = threadIdx.x & 63;
  const float* x = X + (size_t)row * BH + lane * 8;
  f32x4 v0 = *(const f32x4*)x;
  f32x4 v1 = *(const f32x4*)(x + 4);
  f32x4 w0 = *(const f32x4*)(w + lane * 8);
  f32x4 w1 = *(const f32x4*)(w + lane * 8 + 4);
  float s = v0[0] * w0[0] + v0[1] * w0[1] + v0[2] * w0[2] + v0[3] * w0[3] +
            v1[0] * w1[0] + v1[1] * w1[1] + v1[2] * w1[2] + v1[3] * w1[3];
#pragma unroll
  for (int off = 32; off; off >>= 1) s += __shfl_down(s, off);
  if (lane == 0) rd[row] = s;
  bf16x8 o;
#pragma unroll
  for (int j = 0; j < 4; ++j) { o[j] = f2bf(v0[j]); o[4 + j] = f2bf(v1[j]); }
  *(bf16x8*)(Xbf + (size_t)row * BH + lane * 8) = o;
}

__global__ void k_cvtC_fused(const float* __restrict__ X, const float* __restrict__ wc,
                             const float* __restrict__ wm, short* __restrict__ Xbf,
                             short* __restrict__ Xw, float* __restrict__ rd, int writeXbf) {
  int row = blockIdx.x * 4 + (threadIdx.x >> 6);
  int lane = threadIdx.x & 63;
  const float* x = X + (size_t)row * BH + lane * 8;
  f32x4 v0 = *(const f32x4*)x;
  f32x4 v1 = *(const f32x4*)(x + 4);
  f32x4 c0 = *(const f32x4*)(wc + lane * 8);
  f32x4 c1 = *(const f32x4*)(wc + lane * 8 + 4);
  f32x4 m0 = *(const f32x4*)(wm + lane * 8);
  f32x4 m1 = *(const f32x4*)(wm + lane * 8 + 4);
  float s = v0[0] * c0[0] + v0[1] * c0[1] + v0[2] * c0[2] + v0[3] * c0[3] +
            v1[0] * c1[0] + v1[1] * c1[1] + v1[2] * c1[2] + v1[3] * c1[3];
#pragma unroll
  for (int off = 32; off; off >>= 1) s += __shfl_down(s, off);
  if (lane == 0) rd[row] = s;
  bf16x8 ow;
#pragma unroll
  for (int j = 0; j < 4; ++j) { ow[j] = f2bf(v0[j] * m0[j]); ow[4 + j] = f2bf(v1[j] * m1[j]); }
  *(bf16x8*)(Xw + (size_t)row * BH + lane * 8) = ow;
  if (writeXbf) {
    bf16x8 ob;
#pragma unroll
    for (int j = 0; j < 4; ++j) { ob[j] = f2bf(v0[j]); ob[4 + j] = f2bf(v1[j]); }
    *(bf16x8*)(Xbf + (size_t)row * BH + lane * 8) = ob;
  }
}

// prjT[n][k] = bf16(prj[k][n]); k=2048, n=512
__global__ void k_prjT(const float* __restrict__ prj, short* __restrict__ prjT) {
  __shared__ float t[32][33];
  int k0 = blockIdx.x * 32, n0 = blockIdx.y * 32;
  int x = threadIdx.x & 31, y = threadIdx.x >> 5;  // 32x8
  for (int yy = y; yy < 32; yy += 8)
    t[yy][x] = prj[(size_t)(k0 + yy) * BH + n0 + x];
  __syncthreads();
  for (int yy = y; yy < 32; yy += 8)
    prjT[(size_t)(n0 + yy) * 2048 + k0 + x] = f2bf(t[x][yy]);
}

// WT[kb][o][s] = bf16(W[kb][s][o]); s<1536 only
__global__ void k_WT(const float* __restrict__ W, short* __restrict__ WT) {
  __shared__ float t[32][33];
  int s0 = blockIdx.x * 32, o0 = blockIdx.y * 32, kb = blockIdx.z;
  const float* Wk = W + (size_t)kb * SUB_IN * BH;
  int x = threadIdx.x & 31, y = threadIdx.x >> 5;
  for (int yy = y; yy < 32; yy += 8)
    t[yy][x] = Wk[(size_t)(s0 + yy) * BH + o0 + x];
  __syncthreads();
  for (int yy = y; yy < 32; yy += 8)
    WT[((size_t)kb * BH + o0 + yy) * 1536 + s0 + x] = f2bf(t[x][yy]);
}

// out[b,kb,o] = rew[b]*W[kb,1536,o] + bias[kb,o]  (seed for split-K atomics)
__global__ void k_init(const float* __restrict__ rew, const float* __restrict__ W,
                       const float* __restrict__ bias, float* __restrict__ out) {
  int i = blockIdx.x * 256 + threadIdx.x;  // over BS*KN*BH/4
  int o4 = i & 127;
  int kb = (i >> 7) & 63;
  int b = i >> 13;
  f32x4 w = *(const f32x4*)(W + (size_t)kb * SUB_IN * BH + (size_t)1536 * BH + o4 * 4);
  f32x4 bi = *(const f32x4*)(bias + (size_t)kb * BH + o4 * 4);
  float rv = rew[b];
  f32x4 v;
#pragma unroll
  for (int j = 0; j < 4; ++j) v[j] = bi[j] + rv * w[j];
  ((f32x4*)out)[i] = v;
}

// ---------------- staging helpers (64x64 bf16 tile into SWZ'd LDS) ----------------

__device__ __forceinline__ void stage_nat(const short* __restrict__ src, size_t ld,
                                          short* As, int tid) {
  int kl = (tid & 15) * 4;
#pragma unroll
  for (int it = 0; it < 4; ++it) {
    int row = (tid >> 4) + it * 16;
    short4 v = *(const short4*)(src + (size_t)row * ld + kl);
    *(short4*)((char*)As + SWZ(row, row * 128 + kl * 2)) = v;
  }
}

__device__ __forceinline__ void stage_tr(const short* __restrict__ src, size_t ld,
                                         short* Bs, int tid) {
  int n0 = (tid & 15) * 4;
  int k0 = (tid >> 4) * 4;
  short4 r0 = *(const short4*)(src + (size_t)(k0 + 0) * ld + n0);
  short4 r1 = *(const short4*)(src + (size_t)(k0 + 1) * ld + n0);
  short4 r2 = *(const short4*)(src + (size_t)(k0 + 2) * ld + n0);
  short4 r3 = *(const short4*)(src + (size_t)(k0 + 3) * ld + n0);
  *(short4*)((char*)Bs + SWZ(n0 + 0, (n0 + 0) * 128 + k0 * 2)) = make_short4(r0.x, r1.x, r2.x, r3.x);
  *(short4*)((char*)Bs + SWZ(n0 + 1, (n0 + 1) * 128 + k0 * 2)) = make_short4(r0.y, r1.y, r2.y, r3.y);
  *(short4*)((char*)Bs + SWZ(n0 + 2, (n0 + 2) * 128 + k0 * 2)) = make_short4(r0.z, r1.z, r2.z, r3.z);
  *(short4*)((char*)Bs + SWZ(n0 + 3, (n0 + 3) * 128 + k0 * 2)) = make_short4(r0.w, r1.w, r2.w, r3.w);
}

__device__ __forceinline__ void mfma64(const short* As, const short* Bs,
                                       f32x4 acc[4], int lane, int m0) {
#pragma unroll
  for (int kb = 0; kb < 2; ++kb) {
    int k16 = kb * 32 + (lane >> 4) * 8;
    int arow = m0 + (lane & 15);
    bf16x8 af = *(const bf16x8*)((const char*)As + SWZ(arow, arow * 128 + k16 * 2));
#pragma unroll
    for (int f = 0; f < 4; ++f) {
      int nrow = f * 16 + (lane & 15);
      bf16x8 bfr = *(const bf16x8*)((const char*)Bs + SWZ(nrow, nrow * 128 + k16 * 2));
      acc[f] = __builtin_amdgcn_mfma_f32_16x16x32_bf16(af, bfr, acc[f], 0, 0, 0);
    }
  }
}

// ---------------- fused score + dual softmax ----------------
// One block per b: full 64c x 256q tile. 512 threads, 8 waves (4M x 2N).
// Writes S1 = softmax over q (qmask), S2 = softmax over c (cmask), both bf16.
__global__ void k_score2(const short* __restrict__ Cw, const short* __restrict__ Qbf,
                         const float* __restrict__ cw, const float* __restrict__ qw,
                         const float* __restrict__ bias, const float* __restrict__ cmask,
                         const float* __restrict__ qmask,
                         short* __restrict__ S1, short* __restrict__ S2) {
  const int b = blockIdx.x;
  const int tid = threadIdx.x, lane = tid & 63, wave = tid >> 6;
  const int l15 = lane & 15, g4 = lane >> 4;
  const int m0 = (wave >> 1) * 16;      // c-rows of this wave
  const int qh = (wave & 1) * 128;      // q-half of this wave
  __shared__ __align__(16) short As[64 * 64];    // Cw tile (8 KB)
  __shared__ __align__(16) short Bs[256 * 64];   // Q tile (32 KB)
  f32x4 acc[8] = {};
  const short* Cb = Cw + (size_t)b * KN * BH;
  const short* Qb = Qbf + (size_t)b * LQ * BH;

  for (int kk = 0; kk < BH; kk += 64) {
    {
      int row = tid >> 3, ls = tid & 7;
      bf16x8 v = *(const bf16x8*)(Cb + (size_t)row * BH + kk + ls * 8);
      *(bf16x8*)((char*)As + SWZ(row, row * 128 + ls * 16)) = v;
    }
    {
#pragma unroll
      for (int it = 0; it < 2; ++it) {
        int row = it * 128 + (tid >> 2);
        int s0 = (tid & 3) * 2;
#pragma unroll
        for (int u = 0; u < 2; ++u) {
          bf16x8 v = *(const bf16x8*)(Qb + (size_t)row * BH + kk + (s0 + u) * 8);
          *(bf16x8*)((char*)Bs + SWZ(row, row * 128 + (s0 + u) * 16)) = v;
        }
      }
    }
    __syncthreads();
#pragma unroll
    for (int kb2 = 0; kb2 < 2; ++kb2) {
      int k16 = kb2 * 32 + g4 * 8;
      int arow = m0 + l15;
      bf16x8 af = *(const bf16x8*)((const char*)As + SWZ(arow, arow * 128 + k16 * 2));
#pragma unroll
      for (int f = 0; f < 8; ++f) {
        int nrow = qh + f * 16 + l15;
        bf16x8 bfr = *(const bf16x8*)((const char*)Bs + SWZ(nrow, nrow * 128 + k16 * 2));
        acc[f] = __builtin_amdgcn_mfma_f32_16x16x32_bf16(af, bfr, acc[f], 0, 0, 0);
      }
    }
    __syncthreads();
  }

  // epilogue: sraw + both masked softmaxes
  const float bv = bias[0];
  float cmv[4], cwv[4], qmv[8], qwv[8];
#pragma unroll
  for (int e = 0; e < 4; ++e) {
    int c = m0 + g4 * 4 + e;
    cmv[e] = cmask[b * KN + c];
    cwv[e] = cw[b * KN + c];
  }
#pragma unroll
  for (int f = 0; f < 8; ++f) {
    int q = qh + f * 16 + l15;
    qmv[f] = qmask[b * LQ + q];
    qwv[f] = qw[b * LQ + q] + bv;
  }
  float sraw[8][4];
#pragma unroll
  for (int f = 0; f < 8; ++f)
#pragma unroll
    for (int e = 0; e < 4; ++e) sraw[f][e] = acc[f][e] + cwv[e] + qwv[f];

  float* red = (float*)As;          // 8*128 floats (4 KB)
  float* red2 = (float*)As + 1024;  // 8*16
  float* red3 = (float*)As + 1152;  // 8*16

  // ---- c-softmax (per q, over 64 c), mask = cmask ----
  float wmax[8];
#pragma unroll
  for (int f = 0; f < 8; ++f) {
    float m = -1e30f;
#pragma unroll
    for (int e = 0; e < 4; ++e) m = fmaxf(m, clip15(sraw[f][e]) * cmv[e]);
    m = fmaxf(m, __shfl_xor(m, 16));
    m = fmaxf(m, __shfl_xor(m, 32));
    wmax[f] = m;
  }
  if (g4 == 0) {
#pragma unroll
    for (int f = 0; f < 8; ++f) red[wave * 128 + f * 16 + l15] = wmax[f];
  }
  __syncthreads();
  float cmax[8];
#pragma unroll
  for (int f = 0; f < 8; ++f) {
    int base = (wave & 1) * 128 + f * 16 + l15;
    float m = red[base];
#pragma unroll
    for (int w2 = 1; w2 < 4; ++w2) m = fmaxf(m, red[w2 * 256 + base]);
    cmax[f] = m;
  }
  __syncthreads();
  float wsum[8];
#pragma unroll
  for (int f = 0; f < 8; ++f) {
    float s = 0.f;
#pragma unroll
    for (int e = 0; e < 4; ++e) s += __expf(clip15(sraw[f][e]) * cmv[e] - cmax[f]) * cmv[e];
    s += __shfl_xor(s, 16);
    s += __shfl_xor(s, 32);
    wsum[f] = s;
  }
  if (g4 == 0) {
#pragma unroll
    for (int f = 0; f < 8; ++f) red[wave * 128 + f * 16 + l15] = wsum[f];
  }
  __syncthreads();
  float cinv[8];
#pragma unroll
  for (int f = 0; f < 8; ++f) {
    int base = (wave & 1) * 128 + f * 16 + l15;
    float s = 0.f;
#pragma unroll
    for (int w2 = 0; w2 < 4; ++w2) s += red[w2 * 256 + base];
    cinv[f] = 1.f / (s + 1e-6f);
  }
  __syncthreads();

  // ---- q-softmax (per c, over 256 q), mask = qmask ----
  float qmaxl[4];
#pragma unroll
  for (int e = 0; e < 4; ++e) {
    float m = -1e30f;
#pragma unroll
    for (int f = 0; f < 8; ++f) m = fmaxf(m, clip15(sraw[f][e]) * qmv[f]);
#pragma unroll
    for (int off = 8; off; off >>= 1) m = fmaxf(m, __shfl_xor(m, off));
    qmaxl[e] = m;
  }
  if (l15 == 0) {
#pragma unroll
    for (int e = 0; e < 4; ++e) red2[wave * 16 + g4 * 4 + e] = qmaxl[e];
  }
  __syncthreads();
  float qmax[4];
#pragma unroll
  for (int e = 0; e < 4; ++e)
    qmax[e] = fmaxf(red2[wave * 16 + g4 * 4 + e], red2[(wave ^ 1) * 16 + g4 * 4 + e]);
  float qsuml[4];
#pragma unroll
  for (int e = 0; e < 4; ++e) {
    float s = 0.f;
#pragma unroll
    for (int f = 0; f < 8; ++f) s += __expf(clip15(sraw[f][e]) * qmv[f] - qmax[e]) * qmv[f];
#pragma unroll
    for (int off = 8; off; off >>= 1) s += __shfl_xor(s, off);
    qsuml[e] = s;
  }
  if (l15 == 0) {
#pragma unroll
    for (int e = 0; e < 4; ++e) red3[wave * 16 + g4 * 4 + e] = qsuml[e];
  }
  __syncthreads();
  float qinv[4];
#pragma unroll
  for (int e = 0; e < 4; ++e)
    qinv[e] = 1.f / (red3[wave * 16 + g4 * 4 + e] + red3[(wave ^ 1) * 16 + g4 * 4 + e] + 1e-6f);

  // ---- writes ----
#pragma unroll
  for (int f = 0; f < 8; ++f) {
    int q = qh + f * 16 + l15;
#pragma unroll
    for (int e = 0; e < 4; ++e) {
      int c = m0 + g4 * 4 + e;
      size_t gi = ((size_t)b * KN + c) * LQ + q;
      float xq = clip15(sraw[f][e]) * qmv[f];
      float xc = clip15(sraw[f][e]) * cmv[e];
      S1[gi] = f2bf(__expf(xq - qmax[e]) * qmv[f] * qinv[e]);
      S2[gi] = f2bf(__expf(xc - cmax[f]) * cmv[e] * cinv[f]);
    }
  }
}

// ---------------- remaining MFMA pipeline kernels ----------------

__global__ void k_gemm_A_mfma(const short* __restrict__ S1, const short* __restrict__ Qbf,
                              const short* __restrict__ node_bf,
                              short* __restrict__ A_bf, short* __restrict__ CA_bf) {
  const int b = blockIdx.x, d0 = blockIdx.y * 64;
  const int tid = threadIdx.x, lane = tid & 63, m0 = (tid >> 6) * 16;
  __shared__ __align__(16) short As[64 * 64];
  __shared__ __align__(16) short Bs[64 * 64];
  f32x4 acc[4] = {};
  const short* S1b = S1 + (size_t)b * KN * LQ;
  const short* Qb = Qbf + (size_t)b * LQ * BH;
  for (int kk = 0; kk < LQ; kk += 64) {
    stage_nat(S1b + kk, LQ, As, tid);
    stage_tr(Qb + (size_t)kk * BH + d0, BH, Bs, tid);
    __syncthreads();
    mfma64(As, Bs, acc, lane, m0);
    __syncthreads();
  }
  const short* nb = node_bf + (size_t)b * KN * BH;
#pragma unroll
  for (int f = 0; f < 4; ++f) {
    int d = d0 + f * 16 + (lane & 15);
#pragma unroll
    for (int e = 0; e < 4; ++e) {
      int c = m0 + (lane >> 4) * 4 + e;
      size_t gi = ((size_t)b * KN + c) * BH + d;
      float av = acc[f][e];
      A_bf[gi] = f2bf(av);
      CA_bf[gi] = f2bf(bf2f(nb[(size_t)c * BH + d]) * av);
    }
  }
}

__global__ void k_gemm_T_mfma(const short* __restrict__ S1, const short* __restrict__ S2,
                              short* __restrict__ T) {
  const int b = blockIdx.x;
  const int tid = threadIdx.x, lane = tid & 63, m0 = (tid >> 6) * 16;
  __shared__ __align__(16) short As[64 * 64];
  __shared__ __align__(16) short Bs[64 * 64];
  f32x4 acc[4] = {};
  const short* S1b = S1 + (size_t)b * KN * LQ;
  const short* S2b = S2 + (size_t)b * KN * LQ;
  for (int kk = 0; kk < LQ; kk += 64) {
    stage_nat(S1b + kk, LQ, As, tid);
    stage_nat(S2b + kk, LQ, Bs, tid);
    __syncthreads();
    mfma64(As, Bs, acc, lane, m0);
    __syncthreads();
  }
#pragma unroll
  for (int f = 0; f < 4; ++f) {
    int k2 = f * 16 + (lane & 15);
#pragma unroll
    for (int e = 0; e < 4; ++e) {
      int c = m0 + (lane >> 4) * 4 + e;
      T[((size_t)b * KN + c) * KN + k2] = f2bf(acc[f][e]);
    }
  }
}

__global__ void k_gemm_B_mfma(const short* __restrict__ T, const short* __restrict__ node_bf,
                              short* __restrict__ CB_bf) {
  const int b = blockIdx.x, d0 = blockIdx.y * 64;
  const int tid = threadIdx.x, lane = tid & 63, m0 = (tid >> 6) * 16;
  __shared__ __align__(16) short As[64 * 64];
  __shared__ __align__(16) short Bs[64 * 64];
  f32x4 acc[4] = {};
  const short* nb = node_bf + (size_t)b * KN * BH;
  stage_nat(T + (size_t)b * KN * KN, KN, As, tid);
  stage_tr(nb + d0, BH, Bs, tid);
  __syncthreads();
  mfma64(As, Bs, acc, lane, m0);
#pragma unroll
  for (int f = 0; f < 4; ++f) {
    int d = d0 + f * 16 + (lane & 15);
#pragma unroll
    for (int e = 0; e < 4; ++e) {
      int c = m0 + (lane >> 4) * 4 + e;
      CB_bf[((size_t)b * KN + c) * BH + d] = f2bf(bf2f(nb[(size_t)c * BH + d]) * acc[f][e]);
    }
  }
}

__global__ void k_proj_mfma(const short* __restrict__ node_bf, const short* __restrict__ A_bf,
                            const short* __restrict__ CA_bf, const short* __restrict__ CB_bf,
                            const short* __restrict__ prjT, short* __restrict__ H) {
  const int b = blockIdx.x, o0 = blockIdx.y * 64;
  const int tid = threadIdx.x, lane = tid & 63, m0 = (tid >> 6) * 16;
  __shared__ __align__(16) short As[2][64 * 64];
  __shared__ __align__(16) short Bs[2][64 * 64];
  f32x4 acc[4] = {};
  size_t boff = (size_t)b * KN * BH;
  const short* segp[4] = {node_bf + boff, A_bf + boff, CA_bf + boff, CB_bf + boff};
  const short* pT = prjT + (size_t)o0 * 2048;
  for (int kk = 0; kk < 4 * BH; kk += 128) {
#pragma unroll
    for (int h = 0; h < 2; ++h) {
      int k2 = kk + h * 64;
      stage_nat(segp[k2 >> 9] + (k2 & 511), BH, As[h], tid);
      stage_nat(pT + k2, 2048, Bs[h], tid);
    }
    __syncthreads();
    mfma64(As[0], Bs[0], acc, lane, m0);
    mfma64(As[1], Bs[1], acc, lane, m0);
    __syncthreads();
  }
#pragma unroll
  for (int f = 0; f < 4; ++f) {
    int o = o0 + f * 16 + (lane & 15);
#pragma unroll
    for (int e = 0; e < 4; ++e) {
      int c = m0 + (lane >> 4) * 4 + e;
      H[((size_t)b * KN + c) * BH + o] = f2bf(acc[f][e]);
    }
  }
}

// Split-K=3 grouped GEMM with atomic f32 epilogue; single-buffer gload_lds;
// kb-chunked XCD swizzle (each XCD owns 8 consecutive kb).
__global__ void k_blk_mfma(const short* __restrict__ Hno, const short* __restrict__ Hna,
                           const short* __restrict__ node_bf,
                           const short* __restrict__ WT, float* __restrict__ out) {
  const int bid = blockIdx.x;          // 1536
  const int xcd = bid & 7;
  const int s = bid >> 3;              // 0..191
  const int kb = (xcd << 3) + (s / 24);
  const int r = s % 24;
  const int split = r >> 3;            // 0..2 == segment
  const int t8 = r & 7;
  const int b0 = (t8 & 1) * 128, o0 = (t8 >> 1) * 128;
  const int tid = threadIdx.x, lane = tid & 63, wave = tid >> 6, m0 = (tid >> 6) * 32;
  __shared__ __align__(16) short As[128 * 64];
  __shared__ __align__(16) short Bs[128 * 64];
  f32x4 acc[16] = {};
  const short* segs[3] = {Hno, Hna, node_bf};
  const short* Aseg = segs[split] + (size_t)kb * BH;
  const short* Bbase = WT + ((size_t)kb * BH + o0) * 1536 + split * 512;
  const int wh = wave & 1;
  const int lr = lane >> 3;
  const int ls = lane & 7;

  for (int t = 0; t < 8; ++t) {
    const int d = t * 64;
    if (wave < 2) {
#pragma unroll
      for (int c = 0; c < 8; ++c) {
        int row = wh * 64 + c * 8 + lr;
        int sw = ls ^ ((row ^ (row >> 3)) & 7);
        gl_lds16(Aseg + (size_t)(b0 + row) * (KN * BH) + d + sw * 8,
                 As + wh * 4096 + c * 512);
      }
    } else {
#pragma unroll
      for (int c = 0; c < 8; ++c) {
        int row = wh * 64 + c * 8 + lr;
        int sw = ls ^ ((row ^ (row >> 3)) & 7);
        gl_lds16(Bbase + (size_t)row * 1536 + d + sw * 8,
                 Bs + wh * 4096 + c * 512);
      }
    }
    __syncthreads();
#pragma unroll
    for (int kb2 = 0; kb2 < 2; ++kb2) {
      int k16 = kb2 * 32 + (lane >> 4) * 8;
#pragma unroll
      for (int mi = 0; mi < 2; ++mi) {
        int arow = m0 + mi * 16 + (lane & 15);
        bf16x8 af = *(const bf16x8*)((const char*)As + SWZ(arow, arow * 128 + k16 * 2));
#pragma unroll
        for (int f = 0; f < 8; ++f) {
          int nrow = f * 16 + (lane & 15);
          bf16x8 bfr = *(const bf16x8*)((const char*)Bs + SWZ(nrow, nrow * 128 + k16 * 2));
          acc[mi * 8 + f] = __builtin_amdgcn_mfma_f32_16x16x32_bf16(af, bfr, acc[mi * 8 + f], 0, 0, 0);
        }
      }
    }
    __syncthreads();
  }
#pragma unroll
  for (int mi = 0; mi < 2; ++mi) {
#pragma unroll
    for (int f = 0; f < 8; ++f) {
      int o = o0 + f * 16 + (lane & 15);
#pragma unroll
      for (int e = 0; e < 4; ++e) {
        int bb = b0 + m0 + mi * 16 + (lane >> 4) * 4 + e;
        atomicAdd(out + ((size_t)bb * KN + kb) * BH + o, acc[mi * 8 + f][e]);
      }
    }
  }
}

extern "C" void kernel_launch(void* const* d_in, const int* in_sizes, int n_in,
                              void* d_out, int out_size, void* d_ws, size_t ws_size,
                              hipStream_t stream) {
  (void)in_sizes; (void)n_in; (void)out_size; (void)ws_size;
  const float* act   = (const float*)d_in[0];
  const float* obs   = (const float*)d_in[1];
  const float* amask = (const float*)d_in[2];
  const float* omask = (const float*)d_in[3];
  const float* rew   = (const float*)d_in[4];
  const float* node  = (const float*)d_in[5];
  const float* nmask = (const float*)d_in[6];
  const float* w4C_o = (const float*)d_in[7];
  const float* w4Q_o = (const float*)d_in[8];
  const float* w4m_o = (const float*)d_in[9];
  const float* bias_o= (const float*)d_in[10];
  const float* w4C_a = (const float*)d_in[11];
  const float* w4Q_a = (const float*)d_in[12];
  const float* w4m_a = (const float*)d_in[13];
  const float* bias_a= (const float*)d_in[14];
  const float* prj_o = (const float*)d_in[15];
  const float* prj_a = (const float*)d_in[16];
  const float* blkW  = (const float*)d_in[17];
  const float* blkb  = (const float*)d_in[18];
  float* out = (float*)d_out;

  char* wsb = (char*)d_ws;
  auto alloc = [&](size_t bytes) { char* p = wsb; wsb += (bytes + 255) & ~255ull; return p; };
  const size_t NKB = (size_t)BS * KN * BH;   // 8.4M elems
  const size_t NQB = (size_t)BS * LQ * BH;   // 33.6M elems
  short* node_bf = (short*)alloc(NKB * 2);
  short* CwCA    = (short*)alloc(NKB * 2);   // Cw during score; CA after gemm_A
  short* prjT    = (short*)alloc((size_t)2048 * BH * 2);
  // WT aliases the next 4 regions (exactly 100,663,296 B), all dead by k_WT time
  short* Q_bf    = (short*)alloc(NQB * 2);
  short* CB      = (short*)alloc(NKB * 2);
  short* S1      = (short*)alloc((size_t)BS * KN * LQ * 2);
  short* S2      = (short*)alloc((size_t)BS * KN * LQ * 2);
  short* WT      = (short*)Q_bf;             // [64][512][1536] bf16
  short* A_bf    = (short*)alloc(NKB * 2);
  short* T_bf    = (short*)alloc((size_t)BS * KN * KN * 2);
  short* Hno     = (short*)alloc(NKB * 2);
  short* Hna     = (short*)alloc(NKB * 2);
  float* cw      = (float*)alloc((size_t)BS * KN * 4);
  float* qw      = (float*)alloc((size_t)BS * LQ * 4);

  for (int head = 0; head < 2; ++head) {
    const float* Qseq  = head ? act : obs;
    const float* qmask = head ? amask : omask;
    const float* w4C   = head ? w4C_a : w4C_o;
    const float* w4Q   = head ? w4Q_a : w4Q_o;
    const float* w4m   = head ? w4m_a : w4m_o;
    const float* bias  = head ? bias_a : bias_o;
    const float* prj   = head ? prj_a : prj_o;
    short* H = head ? Hna : Hno;

    k_cvtQ_fused<<<dim3(BS * LQ / 4), 256, 0, stream>>>(Qseq, w4Q, Q_bf, qw);
    k_cvtC_fused<<<dim3(BS * KN / 4), 256, 0, stream>>>(node, w4C, w4m, node_bf, CwCA, cw,
                                                        head == 0 ? 1 : 0);
    k_prjT<<<dim3(64, 16), 256, 0, stream>>>(prj, prjT);
    k_score2<<<dim3(BS), 512, 0, stream>>>(CwCA, Q_bf, cw, qw, bias, nmask, qmask, S1, S2);
    k_gemm_A_mfma<<<dim3(BS, BH / 64), 256, 0, stream>>>(S1, Q_bf, node_bf, A_bf, CwCA);
    k_gemm_T_mfma<<<dim3(BS), 256, 0, stream>>>(S1, S2, T_bf);
    k_gemm_B_mfma<<<dim3(BS, BH / 64), 256, 0, stream>>>(T_bf, node_bf, CB);
    k_proj_mfma<<<dim3(BS, BH / 64), 256, 0, stream>>>(node_bf, A_bf, CwCA, CB, prjT, H);
  }
  // WT overwrites Q_bf/CB/S1/S2 (dead after head loop)
  k_WT<<<dim3(48, 16, 64), 256, 0, stream>>>(blkW, WT);
  k_init<<<dim3((int)(NKB / 4 / 256)), 256, 0, stream>>>(rew, blkW, blkb, out);
  k_blk_mfma<<<dim3(1536), 256, 0, stream>>>(Hno, Hna, node_bf, WT, out);
}

// Round 8
// 554.572 us; speedup vs baseline: 1.2609x; 1.2400x over previous
//
#include <hip/hip_runtime.h>
#include <math.h>

#define BS 256
#define LQ 256
#define KN 64
#define BH 512
#define SUB_IN 1537

typedef __attribute__((ext_vector_type(8))) short bf16x8;
typedef __attribute__((ext_vector_type(4))) float f32x4;

__device__ __forceinline__ float clip15(float x) {
  return fminf(fmaxf(x, -15.f), 15.f);
}
__device__ __forceinline__ short f2bf(float f) {
  unsigned u = __float_as_uint(f);
  u = u + 0x7fffu + ((u >> 16) & 1u);
  return (short)(u >> 16);
}
__device__ __forceinline__ float bf2f(short s) {
  return __uint_as_float(((unsigned)(unsigned short)s) << 16);
}

// XOR swizzle on the 16B slot within each 128B LDS row (proven R2-R7)
#define SWZ(row, byte) ((byte) ^ (((((row) ^ ((row) >> 3)) & 7)) << 4))

// async global->LDS, 16B per lane; LDS dest = wave-uniform base + lane*16
__device__ __forceinline__ void gl_lds16(const short* g, short* l) {
  __builtin_amdgcn_global_load_lds(
      (const __attribute__((address_space(1))) void*)g,
      (__attribute__((address_space(3))) void*)l, 16, 0, 0);
}

// ---------------- prep kernels ----------------

__global__ void k_cvtQ_fused(const float* __restrict__ X, const float* __restrict__ w,
                             short* __restrict__ Xbf, float* __restrict__ rd) {
  int row = blockIdx.x * 4 + (threadIdx.x >> 6);
  int lane = threadIdx.x & 63;
  const float* x = X + (size_t)row * BH + lane * 8;
  f32x4 v0 = *(const f32x4*)x;
  f32x4 v1 = *(const f32x4*)(x + 4);
  f32x4 w0 = *(const f32x4*)(w + lane * 8);
  f32x4 w1 = *(const f32x4*)(w + lane * 8 + 4);
  float s = v0[0] * w0[0] + v0[1] * w0[1] + v0[2] * w0[2] + v0[3] * w0[3] +
            v1[0] * w1[0] + v1[1] * w1[1] + v1[2] * w1[2] + v1[3] * w1[3];
#pragma unroll
  for (int off = 32; off; off >>= 1) s += __shfl_down(s, off);
  if (lane == 0) rd[row] = s;
  bf16x8 o;
#pragma unroll
  for (int j = 0; j < 4; ++j) { o[j] = f2bf(v0[j]); o[4 + j] = f2bf(v1[j]); }
  *(bf16x8*)(Xbf + (size_t)row * BH + lane * 8) = o;
}

__global__ void k_cvtC_fused(const float* __restrict__ X, const float* __restrict__ wc,
                             const float* __restrict__ wm, short* __restrict__ Xbf,
                             short* __restrict__ Xw, float* __restrict__ rd, int writeXbf) {
  int row = blockIdx.x * 4 + (threadIdx.x >> 6);
  int lane = threadIdx.x & 63;
  const float* x = X + (size_t)row * BH + lane * 8;
  f32x4 v0 = *(const f32x4*)x;
  f32x4 v1 = *(const f32x4*)(x + 4);
  f32x4 c0 = *(const f32x4*)(wc + lane * 8);
  f32x4 c1 = *(const f32x4*)(wc + lane * 8 + 4);
  f32x4 m0 = *(const f32x4*)(wm + lane * 8);
  f32x4 m1 = *(const f32x4*)(wm + lane * 8 + 4);
  float s = v0[0] * c0[0] + v0[1] * c0[1] + v0[2] * c0[2] + v0[3] * c0[3] +
            v1[0] * c1[0] + v1[1] * c1[1] + v1[2] * c1[2] + v1[3] * c1[3];
#pragma unroll
  for (int off = 32; off; off >>= 1) s += __shfl_down(s, off);
  if (lane == 0) rd[row] = s;
  bf16x8 ow;
#pragma unroll
  for (int j = 0; j < 4; ++j) { ow[j] = f2bf(v0[j] * m0[j]); ow[4 + j] = f2bf(v1[j] * m1[j]); }
  *(bf16x8*)(Xw + (size_t)row * BH + lane * 8) = ow;
  if (writeXbf) {
    bf16x8 ob;
#pragma unroll
    for (int j = 0; j < 4; ++j) { ob[j] = f2bf(v0[j]); ob[4 + j] = f2bf(v1[j]); }
    *(bf16x8*)(Xbf + (size_t)row * BH + lane * 8) = ob;
  }
}

// prjT[n][k] = bf16(prj[k][n]); k=2048, n=512
__global__ void k_prjT(const float* __restrict__ prj, short* __restrict__ prjT) {
  __shared__ float t[32][33];
  int k0 = blockIdx.x * 32, n0 = blockIdx.y * 32;
  int x = threadIdx.x & 31, y = threadIdx.x >> 5;  // 32x8
  for (int yy = y; yy < 32; yy += 8)
    t[yy][x] = prj[(size_t)(k0 + yy) * BH + n0 + x];
  __syncthreads();
  for (int yy = y; yy < 32; yy += 8)
    prjT[(size_t)(n0 + yy) * 2048 + k0 + x] = f2bf(t[x][yy]);
}

// WT[kb][o][s] = bf16(W[kb][s][o]); s<1536 only
__global__ void k_WT(const float* __restrict__ W, short* __restrict__ WT) {
  __shared__ float t[32][33];
  int s0 = blockIdx.x * 32, o0 = blockIdx.y * 32, kb = blockIdx.z;
  const float* Wk = W + (size_t)kb * SUB_IN * BH;
  int x = threadIdx.x & 31, y = threadIdx.x >> 5;
  for (int yy = y; yy < 32; yy += 8)
    t[yy][x] = Wk[(size_t)(s0 + yy) * BH + o0 + x];
  __syncthreads();
  for (int yy = y; yy < 32; yy += 8)
    WT[((size_t)kb * BH + o0 + yy) * 1536 + s0 + x] = f2bf(t[x][yy]);
}

// ---------------- staging helpers (64x64 bf16 tile into SWZ'd LDS) ----------------

__device__ __forceinline__ void stage_nat(const short* __restrict__ src, size_t ld,
                                          short* As, int tid) {
  int kl = (tid & 15) * 4;
#pragma unroll
  for (int it = 0; it < 4; ++it) {
    int row = (tid >> 4) + it * 16;
    short4 v = *(const short4*)(src + (size_t)row * ld + kl);
    *(short4*)((char*)As + SWZ(row, row * 128 + kl * 2)) = v;
  }
}

__device__ __forceinline__ void stage_tr(const short* __restrict__ src, size_t ld,
                                         short* Bs, int tid) {
  int n0 = (tid & 15) * 4;
  int k0 = (tid >> 4) * 4;
  short4 r0 = *(const short4*)(src + (size_t)(k0 + 0) * ld + n0);
  short4 r1 = *(const short4*)(src + (size_t)(k0 + 1) * ld + n0);
  short4 r2 = *(const short4*)(src + (size_t)(k0 + 2) * ld + n0);
  short4 r3 = *(const short4*)(src + (size_t)(k0 + 3) * ld + n0);
  *(short4*)((char*)Bs + SWZ(n0 + 0, (n0 + 0) * 128 + k0 * 2)) = make_short4(r0.x, r1.x, r2.x, r3.x);
  *(short4*)((char*)Bs + SWZ(n0 + 1, (n0 + 1) * 128 + k0 * 2)) = make_short4(r0.y, r1.y, r2.y, r3.y);
  *(short4*)((char*)Bs + SWZ(n0 + 2, (n0 + 2) * 128 + k0 * 2)) = make_short4(r0.z, r1.z, r2.z, r3.z);
  *(short4*)((char*)Bs + SWZ(n0 + 3, (n0 + 3) * 128 + k0 * 2)) = make_short4(r0.w, r1.w, r2.w, r3.w);
}

__device__ __forceinline__ void mfma64(const short* As, const short* Bs,
                                       f32x4 acc[4], int lane, int m0) {
#pragma unroll
  for (int kb = 0; kb < 2; ++kb) {
    int k16 = kb * 32 + (lane >> 4) * 8;
    int arow = m0 + (lane & 15);
    bf16x8 af = *(const bf16x8*)((const char*)As + SWZ(arow, arow * 128 + k16 * 2));
#pragma unroll
    for (int f = 0; f < 4; ++f) {
      int nrow = f * 16 + (lane & 15);
      bf16x8 bfr = *(const bf16x8*)((const char*)Bs + SWZ(nrow, nrow * 128 + k16 * 2));
      acc[f] = __builtin_amdgcn_mfma_f32_16x16x32_bf16(af, bfr, acc[f], 0, 0, 0);
    }
  }
}

// ---------------- fused score + dual softmax ----------------
__global__ void k_score2(const short* __restrict__ Cw, const short* __restrict__ Qbf,
                         const float* __restrict__ cw, const float* __restrict__ qw,
                         const float* __restrict__ bias, const float* __restrict__ cmask,
                         const float* __restrict__ qmask,
                         short* __restrict__ S1, short* __restrict__ S2) {
  const int b = blockIdx.x;
  const int tid = threadIdx.x, lane = tid & 63, wave = tid >> 6;
  const int l15 = lane & 15, g4 = lane >> 4;
  const int m0 = (wave >> 1) * 16;      // c-rows of this wave
  const int qh = (wave & 1) * 128;      // q-half of this wave
  __shared__ __align__(16) short As[64 * 64];    // Cw tile (8 KB)
  __shared__ __align__(16) short Bs[256 * 64];   // Q tile (32 KB)
  f32x4 acc[8] = {};
  const short* Cb = Cw + (size_t)b * KN * BH;
  const short* Qb = Qbf + (size_t)b * LQ * BH;

  for (int kk = 0; kk < BH; kk += 64) {
    {
      int row = tid >> 3, ls = tid & 7;
      bf16x8 v = *(const bf16x8*)(Cb + (size_t)row * BH + kk + ls * 8);
      *(bf16x8*)((char*)As + SWZ(row, row * 128 + ls * 16)) = v;
    }
    {
#pragma unroll
      for (int it = 0; it < 2; ++it) {
        int row = it * 128 + (tid >> 2);
        int s0 = (tid & 3) * 2;
#pragma unroll
        for (int u = 0; u < 2; ++u) {
          bf16x8 v = *(const bf16x8*)(Qb + (size_t)row * BH + kk + (s0 + u) * 8);
          *(bf16x8*)((char*)Bs + SWZ(row, row * 128 + (s0 + u) * 16)) = v;
        }
      }
    }
    __syncthreads();
#pragma unroll
    for (int kb2 = 0; kb2 < 2; ++kb2) {
      int k16 = kb2 * 32 + g4 * 8;
      int arow = m0 + l15;
      bf16x8 af = *(const bf16x8*)((const char*)As + SWZ(arow, arow * 128 + k16 * 2));
#pragma unroll
      for (int f = 0; f < 8; ++f) {
        int nrow = qh + f * 16 + l15;
        bf16x8 bfr = *(const bf16x8*)((const char*)Bs + SWZ(nrow, nrow * 128 + k16 * 2));
        acc[f] = __builtin_amdgcn_mfma_f32_16x16x32_bf16(af, bfr, acc[f], 0, 0, 0);
      }
    }
    __syncthreads();
  }

  const float bv = bias[0];
  float cmv[4], cwv[4], qmv[8], qwv[8];
#pragma unroll
  for (int e = 0; e < 4; ++e) {
    int c = m0 + g4 * 4 + e;
    cmv[e] = cmask[b * KN + c];
    cwv[e] = cw[b * KN + c];
  }
#pragma unroll
  for (int f = 0; f < 8; ++f) {
    int q = qh + f * 16 + l15;
    qmv[f] = qmask[b * LQ + q];
    qwv[f] = qw[b * LQ + q] + bv;
  }
  float sraw[8][4];
#pragma unroll
  for (int f = 0; f < 8; ++f)
#pragma unroll
    for (int e = 0; e < 4; ++e) sraw[f][e] = acc[f][e] + cwv[e] + qwv[f];

  float* red = (float*)As;          // 8*128 floats (4 KB)
  float* red2 = (float*)As + 1024;  // 8*16
  float* red3 = (float*)As + 1152;  // 8*16

  // ---- c-softmax (per q, over 64 c), mask = cmask ----
  float wmax[8];
#pragma unroll
  for (int f = 0; f < 8; ++f) {
    float m = -1e30f;
#pragma unroll
    for (int e = 0; e < 4; ++e) m = fmaxf(m, clip15(sraw[f][e]) * cmv[e]);
    m = fmaxf(m, __shfl_xor(m, 16));
    m = fmaxf(m, __shfl_xor(m, 32));
    wmax[f] = m;
  }
  if (g4 == 0) {
#pragma unroll
    for (int f = 0; f < 8; ++f) red[wave * 128 + f * 16 + l15] = wmax[f];
  }
  __syncthreads();
  float cmax[8];
#pragma unroll
  for (int f = 0; f < 8; ++f) {
    int base = (wave & 1) * 128 + f * 16 + l15;
    float m = red[base];
#pragma unroll
    for (int w2 = 1; w2 < 4; ++w2) m = fmaxf(m, red[w2 * 256 + base]);
    cmax[f] = m;
  }
  __syncthreads();
  float wsum[8];
#pragma unroll
  for (int f = 0; f < 8; ++f) {
    float s = 0.f;
#pragma unroll
    for (int e = 0; e < 4; ++e) s += __expf(clip15(sraw[f][e]) * cmv[e] - cmax[f]) * cmv[e];
    s += __shfl_xor(s, 16);
    s += __shfl_xor(s, 32);
    wsum[f] = s;
  }
  if (g4 == 0) {
#pragma unroll
    for (int f = 0; f < 8; ++f) red[wave * 128 + f * 16 + l15] = wsum[f];
  }
  __syncthreads();
  float cinv[8];
#pragma unroll
  for (int f = 0; f < 8; ++f) {
    int base = (wave & 1) * 128 + f * 16 + l15;
    float s = 0.f;
#pragma unroll
    for (int w2 = 0; w2 < 4; ++w2) s += red[w2 * 256 + base];
    cinv[f] = 1.f / (s + 1e-6f);
  }
  __syncthreads();

  // ---- q-softmax (per c, over 256 q), mask = qmask ----
  float qmaxl[4];
#pragma unroll
  for (int e = 0; e < 4; ++e) {
    float m = -1e30f;
#pragma unroll
    for (int f = 0; f < 8; ++f) m = fmaxf(m, clip15(sraw[f][e]) * qmv[f]);
#pragma unroll
    for (int off = 8; off; off >>= 1) m = fmaxf(m, __shfl_xor(m, off));
    qmaxl[e] = m;
  }
  if (l15 == 0) {
#pragma unroll
    for (int e = 0; e < 4; ++e) red2[wave * 16 + g4 * 4 + e] = qmaxl[e];
  }
  __syncthreads();
  float qmax[4];
#pragma unroll
  for (int e = 0; e < 4; ++e)
    qmax[e] = fmaxf(red2[wave * 16 + g4 * 4 + e], red2[(wave ^ 1) * 16 + g4 * 4 + e]);
  float qsuml[4];
#pragma unroll
  for (int e = 0; e < 4; ++e) {
    float s = 0.f;
#pragma unroll
    for (int f = 0; f < 8; ++f) s += __expf(clip15(sraw[f][e]) * qmv[f] - qmax[e]) * qmv[f];
#pragma unroll
    for (int off = 8; off; off >>= 1) s += __shfl_xor(s, off);
    qsuml[e] = s;
  }
  if (l15 == 0) {
#pragma unroll
    for (int e = 0; e < 4; ++e) red3[wave * 16 + g4 * 4 + e] = qsuml[e];
  }
  __syncthreads();
  float qinv[4];
#pragma unroll
  for (int e = 0; e < 4; ++e)
    qinv[e] = 1.f / (red3[wave * 16 + g4 * 4 + e] + red3[(wave ^ 1) * 16 + g4 * 4 + e] + 1e-6f);

  // ---- writes ----
#pragma unroll
  for (int f = 0; f < 8; ++f) {
    int q = qh + f * 16 + l15;
#pragma unroll
    for (int e = 0; e < 4; ++e) {
      int c = m0 + g4 * 4 + e;
      size_t gi = ((size_t)b * KN + c) * LQ + q;
      float xq = clip15(sraw[f][e]) * qmv[f];
      float xc = clip15(sraw[f][e]) * cmv[e];
      S1[gi] = f2bf(__expf(xq - qmax[e]) * qmv[f] * qinv[e]);
      S2[gi] = f2bf(__expf(xc - cmax[f]) * cmv[e] * cinv[f]);
    }
  }
}

// ---------------- remaining MFMA pipeline kernels ----------------

__global__ void k_gemm_A_mfma(const short* __restrict__ S1, const short* __restrict__ Qbf,
                              const short* __restrict__ node_bf,
                              short* __restrict__ A_bf, short* __restrict__ CA_bf) {
  const int b = blockIdx.x, d0 = blockIdx.y * 64;
  const int tid = threadIdx.x, lane = tid & 63, m0 = (tid >> 6) * 16;
  __shared__ __align__(16) short As[64 * 64];
  __shared__ __align__(16) short Bs[64 * 64];
  f32x4 acc[4] = {};
  const short* S1b = S1 + (size_t)b * KN * LQ;
  const short* Qb = Qbf + (size_t)b * LQ * BH;
  for (int kk = 0; kk < LQ; kk += 64) {
    stage_nat(S1b + kk, LQ, As, tid);
    stage_tr(Qb + (size_t)kk * BH + d0, BH, Bs, tid);
    __syncthreads();
    mfma64(As, Bs, acc, lane, m0);
    __syncthreads();
  }
  const short* nb = node_bf + (size_t)b * KN * BH;
#pragma unroll
  for (int f = 0; f < 4; ++f) {
    int d = d0 + f * 16 + (lane & 15);
#pragma unroll
    for (int e = 0; e < 4; ++e) {
      int c = m0 + (lane >> 4) * 4 + e;
      size_t gi = ((size_t)b * KN + c) * BH + d;
      float av = acc[f][e];
      A_bf[gi] = f2bf(av);
      CA_bf[gi] = f2bf(bf2f(nb[(size_t)c * BH + d]) * av);
    }
  }
}

__global__ void k_gemm_T_mfma(const short* __restrict__ S1, const short* __restrict__ S2,
                              short* __restrict__ T) {
  const int b = blockIdx.x;
  const int tid = threadIdx.x, lane = tid & 63, m0 = (tid >> 6) * 16;
  __shared__ __align__(16) short As[64 * 64];
  __shared__ __align__(16) short Bs[64 * 64];
  f32x4 acc[4] = {};
  const short* S1b = S1 + (size_t)b * KN * LQ;
  const short* S2b = S2 + (size_t)b * KN * LQ;
  for (int kk = 0; kk < LQ; kk += 64) {
    stage_nat(S1b + kk, LQ, As, tid);
    stage_nat(S2b + kk, LQ, Bs, tid);
    __syncthreads();
    mfma64(As, Bs, acc, lane, m0);
    __syncthreads();
  }
#pragma unroll
  for (int f = 0; f < 4; ++f) {
    int k2 = f * 16 + (lane & 15);
#pragma unroll
    for (int e = 0; e < 4; ++e) {
      int c = m0 + (lane >> 4) * 4 + e;
      T[((size_t)b * KN + c) * KN + k2] = f2bf(acc[f][e]);
    }
  }
}

__global__ void k_gemm_B_mfma(const short* __restrict__ T, const short* __restrict__ node_bf,
                              short* __restrict__ CB_bf) {
  const int b = blockIdx.x, d0 = blockIdx.y * 64;
  const int tid = threadIdx.x, lane = tid & 63, m0 = (tid >> 6) * 16;
  __shared__ __align__(16) short As[64 * 64];
  __shared__ __align__(16) short Bs[64 * 64];
  f32x4 acc[4] = {};
  const short* nb = node_bf + (size_t)b * KN * BH;
  stage_nat(T + (size_t)b * KN * KN, KN, As, tid);
  stage_tr(nb + d0, BH, Bs, tid);
  __syncthreads();
  mfma64(As, Bs, acc, lane, m0);
#pragma unroll
  for (int f = 0; f < 4; ++f) {
    int d = d0 + f * 16 + (lane & 15);
#pragma unroll
    for (int e = 0; e < 4; ++e) {
      int c = m0 + (lane >> 4) * 4 + e;
      CB_bf[((size_t)b * KN + c) * BH + d] = f2bf(bf2f(nb[(size_t)c * BH + d]) * acc[f][e]);
    }
  }
}

__global__ void k_proj_mfma(const short* __restrict__ node_bf, const short* __restrict__ A_bf,
                            const short* __restrict__ CA_bf, const short* __restrict__ CB_bf,
                            const short* __restrict__ prjT, short* __restrict__ H) {
  const int b = blockIdx.x, o0 = blockIdx.y * 64;
  const int tid = threadIdx.x, lane = tid & 63, m0 = (tid >> 6) * 16;
  __shared__ __align__(16) short As[2][64 * 64];
  __shared__ __align__(16) short Bs[2][64 * 64];
  f32x4 acc[4] = {};
  size_t boff = (size_t)b * KN * BH;
  const short* segp[4] = {node_bf + boff, A_bf + boff, CA_bf + boff, CB_bf + boff};
  const short* pT = prjT + (size_t)o0 * 2048;
  for (int kk = 0; kk < 4 * BH; kk += 128) {
#pragma unroll
    for (int h = 0; h < 2; ++h) {
      int k2 = kk + h * 64;
      stage_nat(segp[k2 >> 9] + (k2 & 511), BH, As[h], tid);
      stage_nat(pT + k2, 2048, Bs[h], tid);
    }
    __syncthreads();
    mfma64(As[0], Bs[0], acc, lane, m0);
    mfma64(As[1], Bs[1], acc, lane, m0);
    __syncthreads();
  }
#pragma unroll
  for (int f = 0; f < 4; ++f) {
    int o = o0 + f * 16 + (lane & 15);
#pragma unroll
    for (int e = 0; e < 4; ++e) {
      int c = m0 + (lane >> 4) * 4 + e;
      H[((size_t)b * KN + c) * BH + o] = f2bf(acc[f][e]);
    }
  }
}

// Grouped GEMM, full K=1536, no atomics. Tile 64b x 128o, grid 1024,
// 24 KB LDS -> 6 blocks/CU co-residency for cross-block latency hiding.
// kb-chunked XCD decode: one kb's panels (A 0.8MB + B 1.5MB) live in one XCD L2.
__global__ void k_blk_mfma(const short* __restrict__ Hno, const short* __restrict__ Hna,
                           const short* __restrict__ node_bf, const float* __restrict__ rew,
                           const short* __restrict__ WT, const float* __restrict__ W,
                           const float* __restrict__ bias, float* __restrict__ out) {
  const int l = blockIdx.x;            // 1024
  const int xcd = l & 7;
  const int idx = l >> 3;              // 0..127
  const int kb = xcd * 8 + (idx & 7);
  const int tile = idx >> 3;           // 0..15
  const int b0 = (tile & 3) * 64, o0 = (tile >> 2) * 128;
  const int tid = threadIdx.x, lane = tid & 63, wave = tid >> 6;
  const int l15 = lane & 15, g4 = lane >> 4;
  const int m0 = wave * 16;            // A-rows (batch) of this wave
  __shared__ __align__(16) short As[64 * 64];    // 64 batch x 64 k (8 KB)
  __shared__ __align__(16) short Bs[128 * 64];   // 128 o    x 64 k (16 KB)
  f32x4 acc[8] = {};
  const short* segs[3] = {Hno, Hna, node_bf};
  const short* Bpanel = WT + ((size_t)kb * BH + o0) * 1536;
  const int lr = lane >> 3;   // 0..7 row within call
  const int ls = lane & 7;    // 16B slot within row

  for (int t = 0; t < 24; ++t) {
    const int kk = t * 64;
    const short* Aseg = segs[kk >> 9] + (size_t)kb * BH + (kk & 511);
    // A: wave w stages rows [w*16, w*16+16) in 2 calls of 8 rows
#pragma unroll
    for (int c = 0; c < 2; ++c) {
      int row = wave * 16 + c * 8 + lr;
      int sw = ls ^ ((row ^ (row >> 3)) & 7);
      gl_lds16(Aseg + ((size_t)(b0 + row) * KN) * BH + sw * 8,
               As + (wave * 16 + c * 8) * 64);
    }
    // B: wave w stages rows [w*32, w*32+32) in 4 calls of 8 rows
#pragma unroll
    for (int c = 0; c < 4; ++c) {
      int row = wave * 32 + c * 8 + lr;
      int sw = ls ^ ((row ^ (row >> 3)) & 7);
      gl_lds16(Bpanel + (size_t)row * 1536 + kk + sw * 8,
               Bs + (wave * 32 + c * 8) * 64);
    }
    __syncthreads();
#pragma unroll
    for (int kb2 = 0; kb2 < 2; ++kb2) {
      int k16 = kb2 * 32 + g4 * 8;
      int arow = m0 + l15;
      bf16x8 af = *(const bf16x8*)((const char*)As + SWZ(arow, arow * 128 + k16 * 2));
#pragma unroll
      for (int f = 0; f < 8; ++f) {
        int nrow = f * 16 + l15;
        bf16x8 bfr = *(const bf16x8*)((const char*)Bs + SWZ(nrow, nrow * 128 + k16 * 2));
        acc[f] = __builtin_amdgcn_mfma_f32_16x16x32_bf16(af, bfr, acc[f], 0, 0, 0);
      }
    }
    __syncthreads();
  }
  const float* Wrow = W + (size_t)kb * SUB_IN * BH + (size_t)1536 * BH;
  const float* bkb = bias + kb * BH;
#pragma unroll
  for (int f = 0; f < 8; ++f) {
    int o = o0 + f * 16 + l15;
    float wr = Wrow[o];
    float bv = bkb[o];
#pragma unroll
    for (int e = 0; e < 4; ++e) {
      int bb = b0 + m0 + g4 * 4 + e;
      out[((size_t)bb * KN + kb) * BH + o] = acc[f][e] + rew[bb] * wr + bv;
    }
  }
}

extern "C" void kernel_launch(void* const* d_in, const int* in_sizes, int n_in,
                              void* d_out, int out_size, void* d_ws, size_t ws_size,
                              hipStream_t stream) {
  (void)in_sizes; (void)n_in; (void)out_size; (void)ws_size;
  const float* act   = (const float*)d_in[0];
  const float* obs   = (const float*)d_in[1];
  const float* amask = (const float*)d_in[2];
  const float* omask = (const float*)d_in[3];
  const float* rew   = (const float*)d_in[4];
  const float* node  = (const float*)d_in[5];
  const float* nmask = (const float*)d_in[6];
  const float* w4C_o = (const float*)d_in[7];
  const float* w4Q_o = (const float*)d_in[8];
  const float* w4m_o = (const float*)d_in[9];
  const float* bias_o= (const float*)d_in[10];
  const float* w4C_a = (const float*)d_in[11];
  const float* w4Q_a = (const float*)d_in[12];
  const float* w4m_a = (const float*)d_in[13];
  const float* bias_a= (const float*)d_in[14];
  const float* prj_o = (const float*)d_in[15];
  const float* prj_a = (const float*)d_in[16];
  const float* blkW  = (const float*)d_in[17];
  const float* blkb  = (const float*)d_in[18];
  float* out = (float*)d_out;

  char* wsb = (char*)d_ws;
  auto alloc = [&](size_t bytes) { char* p = wsb; wsb += (bytes + 255) & ~255ull; return p; };
  const size_t NKB = (size_t)BS * KN * BH;   // 8.4M elems
  const size_t NQB = (size_t)BS * LQ * BH;   // 33.6M elems
  short* node_bf = (short*)alloc(NKB * 2);
  short* CwCA    = (short*)alloc(NKB * 2);   // Cw during score; CA after gemm_A
  short* prjT    = (short*)alloc((size_t)2048 * BH * 2);
  // WT aliases the next 4 regions (exactly 100,663,296 B), all dead by k_WT time
  short* Q_bf    = (short*)alloc(NQB * 2);
  short* CB      = (short*)alloc(NKB * 2);
  short* S1      = (short*)alloc((size_t)BS * KN * LQ * 2);
  short* S2      = (short*)alloc((size_t)BS * KN * LQ * 2);
  short* WT      = (short*)Q_bf;             // [64][512][1536] bf16
  short* A_bf    = (short*)alloc(NKB * 2);
  short* T_bf    = (short*)alloc((size_t)BS * KN * KN * 2);
  short* Hno     = (short*)alloc(NKB * 2);
  short* Hna     = (short*)alloc(NKB * 2);
  float* cw      = (float*)alloc((size_t)BS * KN * 4);
  float* qw      = (float*)alloc((size_t)BS * LQ * 4);

  for (int head = 0; head < 2; ++head) {
    const float* Qseq  = head ? act : obs;
    const float* qmask = head ? amask : omask;
    const float* w4C   = head ? w4C_a : w4C_o;
    const float* w4Q   = head ? w4Q_a : w4Q_o;
    const float* w4m   = head ? w4m_a : w4m_o;
    const float* bias  = head ? bias_a : bias_o;
    const float* prj   = head ? prj_a : prj_o;
    short* H = head ? Hna : Hno;

    k_cvtQ_fused<<<dim3(BS * LQ / 4), 256, 0, stream>>>(Qseq, w4Q, Q_bf, qw);
    k_cvtC_fused<<<dim3(BS * KN / 4), 256, 0, stream>>>(node, w4C, w4m, node_bf, CwCA, cw,
                                                        head == 0 ? 1 : 0);
    k_prjT<<<dim3(64, 16), 256, 0, stream>>>(prj, prjT);
    k_score2<<<dim3(BS), 512, 0, stream>>>(CwCA, Q_bf, cw, qw, bias, nmask, qmask, S1, S2);
    k_gemm_A_mfma<<<dim3(BS, BH / 64), 256, 0, stream>>>(S1, Q_bf, node_bf, A_bf, CwCA);
    k_gemm_T_mfma<<<dim3(BS), 256, 0, stream>>>(S1, S2, T_bf);
    k_gemm_B_mfma<<<dim3(BS, BH / 64), 256, 0, stream>>>(T_bf, node_bf, CB);
    k_proj_mfma<<<dim3(BS, BH / 64), 256, 0, stream>>>(node_bf, A_bf, CwCA, CB, prjT, H);
  }
  // WT overwrites Q_bf/CB/S1/S2 (dead after head loop)
  k_WT<<<dim3(48, 16, 64), 256, 0, stream>>>(blkW, WT);
  k_blk_mfma<<<dim3(1024), 256, 0, stream>>>(Hno, Hna, node_bf, rew, WT, blkW, blkb, out);
}

// Round 9
// 524.407 us; speedup vs baseline: 1.3335x; 1.0575x over previous
//
#include <hip/hip_runtime.h>
#include <math.h>

#define BS 256
#define LQ 256
#define KN 64
#define BH 512
#define SUB_IN 1537

typedef __attribute__((ext_vector_type(8))) short bf16x8;
typedef __attribute__((ext_vector_type(4))) float f32x4;

__device__ __forceinline__ float clip15(float x) {
  return fminf(fmaxf(x, -15.f), 15.f);
}
__device__ __forceinline__ short f2bf(float f) {
  unsigned u = __float_as_uint(f);
  u = u + 0x7fffu + ((u >> 16) & 1u);
  return (short)(u >> 16);
}
__device__ __forceinline__ float bf2f(short s) {
  return __uint_as_float(((unsigned)(unsigned short)s) << 16);
}

// XOR swizzle on the 16B slot within each 128B LDS row (proven R2-R8)
#define SWZ(row, byte) ((byte) ^ (((((row) ^ ((row) >> 3)) & 7)) << 4))

// async global->LDS, 16B per lane; LDS dest = wave-uniform base + lane*16
__device__ __forceinline__ void gl_lds16(const short* g, short* l) {
  __builtin_amdgcn_global_load_lds(
      (const __attribute__((address_space(1))) void*)g,
      (__attribute__((address_space(3))) void*)l, 16, 0, 0);
}

// ---------------- prep kernels ----------------

// both heads: convert Q + rowdot with w4Q
__global__ void k_cvtQ2(const float* __restrict__ obs, const float* __restrict__ act,
                        const float* __restrict__ wq_o, const float* __restrict__ wq_a,
                        short* __restrict__ Qbf, float* __restrict__ qw) {
  const int head = blockIdx.y;
  const float* X = head ? act : obs;
  const float* w = head ? wq_a : wq_o;
  short* Xbf = Qbf + (size_t)head * BS * LQ * BH;
  float* rd = qw + head * BS * LQ;
  int row = blockIdx.x * 4 + (threadIdx.x >> 6);
  int lane = threadIdx.x & 63;
  const float* x = X + (size_t)row * BH + lane * 8;
  f32x4 v0 = *(const f32x4*)x;
  f32x4 v1 = *(const f32x4*)(x + 4);
  f32x4 w0 = *(const f32x4*)(w + lane * 8);
  f32x4 w1 = *(const f32x4*)(w + lane * 8 + 4);
  float s = v0[0] * w0[0] + v0[1] * w0[1] + v0[2] * w0[2] + v0[3] * w0[3] +
            v1[0] * w1[0] + v1[1] * w1[1] + v1[2] * w1[2] + v1[3] * w1[3];
#pragma unroll
  for (int off = 32; off; off >>= 1) s += __shfl_down(s, off);
  if (lane == 0) rd[row] = s;
  bf16x8 o;
#pragma unroll
  for (int j = 0; j < 4; ++j) { o[j] = f2bf(v0[j]); o[4 + j] = f2bf(v1[j]); }
  *(bf16x8*)(Xbf + (size_t)row * BH + lane * 8) = o;
}

// one pass over node: node_bf, Cw_o = node*wm_o, Cw_a = node*wm_a, cw_o/cw_a rowdots
__global__ void k_cvtC2(const float* __restrict__ X,
                        const float* __restrict__ wc_o, const float* __restrict__ wc_a,
                        const float* __restrict__ wm_o, const float* __restrict__ wm_a,
                        short* __restrict__ Xbf, short* __restrict__ Xw_o,
                        short* __restrict__ Xw_a,
                        float* __restrict__ rd_o, float* __restrict__ rd_a) {
  int row = blockIdx.x * 4 + (threadIdx.x >> 6);
  int lane = threadIdx.x & 63;
  const float* x = X + (size_t)row * BH + lane * 8;
  f32x4 v0 = *(const f32x4*)x;
  f32x4 v1 = *(const f32x4*)(x + 4);
  f32x4 co0 = *(const f32x4*)(wc_o + lane * 8);
  f32x4 co1 = *(const f32x4*)(wc_o + lane * 8 + 4);
  f32x4 ca0 = *(const f32x4*)(wc_a + lane * 8);
  f32x4 ca1 = *(const f32x4*)(wc_a + lane * 8 + 4);
  float so = v0[0] * co0[0] + v0[1] * co0[1] + v0[2] * co0[2] + v0[3] * co0[3] +
             v1[0] * co1[0] + v1[1] * co1[1] + v1[2] * co1[2] + v1[3] * co1[3];
  float sa = v0[0] * ca0[0] + v0[1] * ca0[1] + v0[2] * ca0[2] + v0[3] * ca0[3] +
             v1[0] * ca1[0] + v1[1] * ca1[1] + v1[2] * ca1[2] + v1[3] * ca1[3];
#pragma unroll
  for (int off = 32; off; off >>= 1) { so += __shfl_down(so, off); sa += __shfl_down(sa, off); }
  if (lane == 0) { rd_o[row] = so; rd_a[row] = sa; }
  f32x4 mo0 = *(const f32x4*)(wm_o + lane * 8);
  f32x4 mo1 = *(const f32x4*)(wm_o + lane * 8 + 4);
  f32x4 ma0 = *(const f32x4*)(wm_a + lane * 8);
  f32x4 ma1 = *(const f32x4*)(wm_a + lane * 8 + 4);
  bf16x8 ob, oo, oa;
#pragma unroll
  for (int j = 0; j < 4; ++j) {
    ob[j] = f2bf(v0[j]);          ob[4 + j] = f2bf(v1[j]);
    oo[j] = f2bf(v0[j] * mo0[j]); oo[4 + j] = f2bf(v1[j] * mo1[j]);
    oa[j] = f2bf(v0[j] * ma0[j]); oa[4 + j] = f2bf(v1[j] * ma1[j]);
  }
  size_t gi = (size_t)row * BH + lane * 8;
  *(bf16x8*)(Xbf + gi) = ob;
  *(bf16x8*)(Xw_o + gi) = oo;
  *(bf16x8*)(Xw_a + gi) = oa;
}

// prjT[head][n][k] = bf16(prj_head[k][n]); k=2048, n=512
__global__ void k_prjT(const float* __restrict__ prj_o, const float* __restrict__ prj_a,
                       short* __restrict__ prjT) {
  __shared__ float t[32][33];
  int k0 = blockIdx.x * 32, n0 = blockIdx.y * 32, head = blockIdx.z;
  const float* prj = head ? prj_a : prj_o;
  short* dst = prjT + (size_t)head * BH * 2048;
  int x = threadIdx.x & 31, y = threadIdx.x >> 5;  // 32x8
  for (int yy = y; yy < 32; yy += 8)
    t[yy][x] = prj[(size_t)(k0 + yy) * BH + n0 + x];
  __syncthreads();
  for (int yy = y; yy < 32; yy += 8)
    dst[(size_t)(n0 + yy) * 2048 + k0 + x] = f2bf(t[x][yy]);
}

// WT[kb][o][s] = bf16(W[kb][s][o]); s<1536 only
__global__ void k_WT(const float* __restrict__ W, short* __restrict__ WT) {
  __shared__ float t[32][33];
  int s0 = blockIdx.x * 32, o0 = blockIdx.y * 32, kb = blockIdx.z;
  const float* Wk = W + (size_t)kb * SUB_IN * BH;
  int x = threadIdx.x & 31, y = threadIdx.x >> 5;
  for (int yy = y; yy < 32; yy += 8)
    t[yy][x] = Wk[(size_t)(s0 + yy) * BH + o0 + x];
  __syncthreads();
  for (int yy = y; yy < 32; yy += 8)
    WT[((size_t)kb * BH + o0 + yy) * 1536 + s0 + x] = f2bf(t[x][yy]);
}

// ---------------- staging helpers (64x64 bf16 tile into SWZ'd LDS) ----------------

__device__ __forceinline__ void stage_nat(const short* __restrict__ src, size_t ld,
                                          short* As, int tid) {
  int kl = (tid & 15) * 4;
#pragma unroll
  for (int it = 0; it < 4; ++it) {
    int row = (tid >> 4) + it * 16;
    short4 v = *(const short4*)(src + (size_t)row * ld + kl);
    *(short4*)((char*)As + SWZ(row, row * 128 + kl * 2)) = v;
  }
}

__device__ __forceinline__ void stage_tr(const short* __restrict__ src, size_t ld,
                                         short* Bs, int tid) {
  int n0 = (tid & 15) * 4;
  int k0 = (tid >> 4) * 4;
  short4 r0 = *(const short4*)(src + (size_t)(k0 + 0) * ld + n0);
  short4 r1 = *(const short4*)(src + (size_t)(k0 + 1) * ld + n0);
  short4 r2 = *(const short4*)(src + (size_t)(k0 + 2) * ld + n0);
  short4 r3 = *(const short4*)(src + (size_t)(k0 + 3) * ld + n0);
  *(short4*)((char*)Bs + SWZ(n0 + 0, (n0 + 0) * 128 + k0 * 2)) = make_short4(r0.x, r1.x, r2.x, r3.x);
  *(short4*)((char*)Bs + SWZ(n0 + 1, (n0 + 1) * 128 + k0 * 2)) = make_short4(r0.y, r1.y, r2.y, r3.y);
  *(short4*)((char*)Bs + SWZ(n0 + 2, (n0 + 2) * 128 + k0 * 2)) = make_short4(r0.z, r1.z, r2.z, r3.z);
  *(short4*)((char*)Bs + SWZ(n0 + 3, (n0 + 3) * 128 + k0 * 2)) = make_short4(r0.w, r1.w, r2.w, r3.w);
}

__device__ __forceinline__ void mfma64(const short* As, const short* Bs,
                                       f32x4 acc[4], int lane, int m0) {
#pragma unroll
  for (int kb = 0; kb < 2; ++kb) {
    int k16 = kb * 32 + (lane >> 4) * 8;
    int arow = m0 + (lane & 15);
    bf16x8 af = *(const bf16x8*)((const char*)As + SWZ(arow, arow * 128 + k16 * 2));
#pragma unroll
    for (int f = 0; f < 4; ++f) {
      int nrow = f * 16 + (lane & 15);
      bf16x8 bfr = *(const bf16x8*)((const char*)Bs + SWZ(nrow, nrow * 128 + k16 * 2));
      acc[f] = __builtin_amdgcn_mfma_f32_16x16x32_bf16(af, bfr, acc[f], 0, 0, 0);
    }
  }
}

// ---------------- fused score + dual softmax (both heads via blockIdx.y) ----------------
__global__ void k_score2(const short* __restrict__ Cw_o, const short* __restrict__ Cw_a,
                         const short* __restrict__ Qbf,
                         const float* __restrict__ cw, const float* __restrict__ qw,
                         const float* __restrict__ bias_o, const float* __restrict__ bias_a,
                         const float* __restrict__ cmask,
                         const float* __restrict__ omask, const float* __restrict__ amask,
                         short* __restrict__ S1, short* __restrict__ S2) {
  const int b = blockIdx.x;
  const int head = blockIdx.y;
  const short* Cb = (head ? Cw_a : Cw_o) + (size_t)b * KN * BH;
  const short* Qb = Qbf + (size_t)head * BS * LQ * BH + (size_t)b * LQ * BH;
  const float* cwh = cw + head * BS * KN;
  const float* qwh = qw + head * BS * LQ;
  const float* qmask = head ? amask : omask;
  const float bv = head ? bias_a[0] : bias_o[0];
  short* S1h = S1 + (size_t)head * BS * KN * LQ;
  short* S2h = S2 + (size_t)head * BS * KN * LQ;
  const int tid = threadIdx.x, lane = tid & 63, wave = tid >> 6;
  const int l15 = lane & 15, g4 = lane >> 4;
  const int m0 = (wave >> 1) * 16;      // c-rows of this wave
  const int qh = (wave & 1) * 128;      // q-half of this wave
  __shared__ __align__(16) short As[64 * 64];    // Cw tile (8 KB)
  __shared__ __align__(16) short Bs[256 * 64];   // Q tile (32 KB)
  f32x4 acc[8] = {};

  for (int kk = 0; kk < BH; kk += 64) {
    {
      int row = tid >> 3, ls = tid & 7;
      bf16x8 v = *(const bf16x8*)(Cb + (size_t)row * BH + kk + ls * 8);
      *(bf16x8*)((char*)As + SWZ(row, row * 128 + ls * 16)) = v;
    }
    {
#pragma unroll
      for (int it = 0; it < 2; ++it) {
        int row = it * 128 + (tid >> 2);
        int s0 = (tid & 3) * 2;
#pragma unroll
        for (int u = 0; u < 2; ++u) {
          bf16x8 v = *(const bf16x8*)(Qb + (size_t)row * BH + kk + (s0 + u) * 8);
          *(bf16x8*)((char*)Bs + SWZ(row, row * 128 + (s0 + u) * 16)) = v;
        }
      }
    }
    __syncthreads();
#pragma unroll
    for (int kb2 = 0; kb2 < 2; ++kb2) {
      int k16 = kb2 * 32 + g4 * 8;
      int arow = m0 + l15;
      bf16x8 af = *(const bf16x8*)((const char*)As + SWZ(arow, arow * 128 + k16 * 2));
#pragma unroll
      for (int f = 0; f < 8; ++f) {
        int nrow = qh + f * 16 + l15;
        bf16x8 bfr = *(const bf16x8*)((const char*)Bs + SWZ(nrow, nrow * 128 + k16 * 2));
        acc[f] = __builtin_amdgcn_mfma_f32_16x16x32_bf16(af, bfr, acc[f], 0, 0, 0);
      }
    }
    __syncthreads();
  }

  float cmv[4], cwv[4], qmv[8], qwv[8];
#pragma unroll
  for (int e = 0; e < 4; ++e) {
    int c = m0 + g4 * 4 + e;
    cmv[e] = cmask[b * KN + c];
    cwv[e] = cwh[b * KN + c];
  }
#pragma unroll
  for (int f = 0; f < 8; ++f) {
    int q = qh + f * 16 + l15;
    qmv[f] = qmask[b * LQ + q];
    qwv[f] = qwh[b * LQ + q] + bv;
  }
  float sraw[8][4];
#pragma unroll
  for (int f = 0; f < 8; ++f)
#pragma unroll
    for (int e = 0; e < 4; ++e) sraw[f][e] = acc[f][e] + cwv[e] + qwv[f];

  float* red = (float*)As;          // 8*128 floats (4 KB)
  float* red2 = (float*)As + 1024;  // 8*16
  float* red3 = (float*)As + 1152;  // 8*16

  // ---- c-softmax (per q, over 64 c), mask = cmask ----
  float wmax[8];
#pragma unroll
  for (int f = 0; f < 8; ++f) {
    float m = -1e30f;
#pragma unroll
    for (int e = 0; e < 4; ++e) m = fmaxf(m, clip15(sraw[f][e]) * cmv[e]);
    m = fmaxf(m, __shfl_xor(m, 16));
    m = fmaxf(m, __shfl_xor(m, 32));
    wmax[f] = m;
  }
  if (g4 == 0) {
#pragma unroll
    for (int f = 0; f < 8; ++f) red[wave * 128 + f * 16 + l15] = wmax[f];
  }
  __syncthreads();
  float cmax[8];
#pragma unroll
  for (int f = 0; f < 8; ++f) {
    int base = (wave & 1) * 128 + f * 16 + l15;
    float m = red[base];
#pragma unroll
    for (int w2 = 1; w2 < 4; ++w2) m = fmaxf(m, red[w2 * 256 + base]);
    cmax[f] = m;
  }
  __syncthreads();
  float wsum[8];
#pragma unroll
  for (int f = 0; f < 8; ++f) {
    float s = 0.f;
#pragma unroll
    for (int e = 0; e < 4; ++e) s += __expf(clip15(sraw[f][e]) * cmv[e] - cmax[f]) * cmv[e];
    s += __shfl_xor(s, 16);
    s += __shfl_xor(s, 32);
    wsum[f] = s;
  }
  if (g4 == 0) {
#pragma unroll
    for (int f = 0; f < 8; ++f) red[wave * 128 + f * 16 + l15] = wsum[f];
  }
  __syncthreads();
  float cinv[8];
#pragma unroll
  for (int f = 0; f < 8; ++f) {
    int base = (wave & 1) * 128 + f * 16 + l15;
    float s = 0.f;
#pragma unroll
    for (int w2 = 0; w2 < 4; ++w2) s += red[w2 * 256 + base];
    cinv[f] = 1.f / (s + 1e-6f);
  }
  __syncthreads();

  // ---- q-softmax (per c, over 256 q), mask = qmask ----
  float qmaxl[4];
#pragma unroll
  for (int e = 0; e < 4; ++e) {
    float m = -1e30f;
#pragma unroll
    for (int f = 0; f < 8; ++f) m = fmaxf(m, clip15(sraw[f][e]) * qmv[f]);
#pragma unroll
    for (int off = 8; off; off >>= 1) m = fmaxf(m, __shfl_xor(m, off));
    qmaxl[e] = m;
  }
  if (l15 == 0) {
#pragma unroll
    for (int e = 0; e < 4; ++e) red2[wave * 16 + g4 * 4 + e] = qmaxl[e];
  }
  __syncthreads();
  float qmax[4];
#pragma unroll
  for (int e = 0; e < 4; ++e)
    qmax[e] = fmaxf(red2[wave * 16 + g4 * 4 + e], red2[(wave ^ 1) * 16 + g4 * 4 + e]);
  float qsuml[4];
#pragma unroll
  for (int e = 0; e < 4; ++e) {
    float s = 0.f;
#pragma unroll
    for (int f = 0; f < 8; ++f) s += __expf(clip15(sraw[f][e]) * qmv[f] - qmax[e]) * qmv[f];
#pragma unroll
    for (int off = 8; off; off >>= 1) s += __shfl_xor(s, off);
    qsuml[e] = s;
  }
  if (l15 == 0) {
#pragma unroll
    for (int e = 0; e < 4; ++e) red3[wave * 16 + g4 * 4 + e] = qsuml[e];
  }
  __syncthreads();
  float qinv[4];
#pragma unroll
  for (int e = 0; e < 4; ++e)
    qinv[e] = 1.f / (red3[wave * 16 + g4 * 4 + e] + red3[(wave ^ 1) * 16 + g4 * 4 + e] + 1e-6f);

  // ---- writes ----
#pragma unroll
  for (int f = 0; f < 8; ++f) {
    int q = qh + f * 16 + l15;
#pragma unroll
    for (int e = 0; e < 4; ++e) {
      int c = m0 + g4 * 4 + e;
      size_t gi = ((size_t)b * KN + c) * LQ + q;
      float xq = clip15(sraw[f][e]) * qmv[f];
      float xc = clip15(sraw[f][e]) * cmv[e];
      S1h[gi] = f2bf(__expf(xq - qmax[e]) * qmv[f] * qinv[e]);
      S2h[gi] = f2bf(__expf(xc - cmax[f]) * cmv[e] * cinv[f]);
    }
  }
}

// ---------------- A/T/B GEMMs (both heads via blockIdx.z / .y) ----------------

__global__ void k_gemm_A_mfma(const short* __restrict__ S1, const short* __restrict__ Qbf,
                              const short* __restrict__ node_bf,
                              short* __restrict__ A_bf, short* __restrict__ CA_bf) {
  const int b = blockIdx.x, d0 = blockIdx.y * 64, head = blockIdx.z;
  const size_t hq = (size_t)head * BS * LQ * BH;
  const size_t hs = (size_t)head * BS * KN * LQ;
  const size_t hk = (size_t)head * BS * KN * BH;
  const int tid = threadIdx.x, lane = tid & 63, m0 = (tid >> 6) * 16;
  __shared__ __align__(16) short As[64 * 64];
  __shared__ __align__(16) short Bs[64 * 64];
  f32x4 acc[4] = {};
  const short* S1b = S1 + hs + (size_t)b * KN * LQ;
  const short* Qb = Qbf + hq + (size_t)b * LQ * BH;
  for (int kk = 0; kk < LQ; kk += 64) {
    stage_nat(S1b + kk, LQ, As, tid);
    stage_tr(Qb + (size_t)kk * BH + d0, BH, Bs, tid);
    __syncthreads();
    mfma64(As, Bs, acc, lane, m0);
    __syncthreads();
  }
  const short* nb = node_bf + (size_t)b * KN * BH;
#pragma unroll
  for (int f = 0; f < 4; ++f) {
    int d = d0 + f * 16 + (lane & 15);
#pragma unroll
    for (int e = 0; e < 4; ++e) {
      int c = m0 + (lane >> 4) * 4 + e;
      size_t gi = ((size_t)b * KN + c) * BH + d;
      float av = acc[f][e];
      A_bf[hk + gi] = f2bf(av);
      CA_bf[hk + gi] = f2bf(bf2f(nb[(size_t)c * BH + d]) * av);
    }
  }
}

__global__ void k_gemm_T_mfma(const short* __restrict__ S1, const short* __restrict__ S2,
                              short* __restrict__ T) {
  const int b = blockIdx.x, head = blockIdx.y;
  const size_t hs = (size_t)head * BS * KN * LQ;
  const int tid = threadIdx.x, lane = tid & 63, m0 = (tid >> 6) * 16;
  __shared__ __align__(16) short As[64 * 64];
  __shared__ __align__(16) short Bs[64 * 64];
  f32x4 acc[4] = {};
  const short* S1b = S1 + hs + (size_t)b * KN * LQ;
  const short* S2b = S2 + hs + (size_t)b * KN * LQ;
  for (int kk = 0; kk < LQ; kk += 64) {
    stage_nat(S1b + kk, LQ, As, tid);
    stage_nat(S2b + kk, LQ, Bs, tid);
    __syncthreads();
    mfma64(As, Bs, acc, lane, m0);
    __syncthreads();
  }
  short* Th = T + (size_t)head * BS * KN * KN;
#pragma unroll
  for (int f = 0; f < 4; ++f) {
    int k2 = f * 16 + (lane & 15);
#pragma unroll
    for (int e = 0; e < 4; ++e) {
      int c = m0 + (lane >> 4) * 4 + e;
      Th[((size_t)b * KN + c) * KN + k2] = f2bf(acc[f][e]);
    }
  }
}

__global__ void k_gemm_B_mfma(const short* __restrict__ T, const short* __restrict__ node_bf,
                              short* __restrict__ CB_bf) {
  const int b = blockIdx.x, d0 = blockIdx.y * 64, head = blockIdx.z;
  const int tid = threadIdx.x, lane = tid & 63, m0 = (tid >> 6) * 16;
  __shared__ __align__(16) short As[64 * 64];
  __shared__ __align__(16) short Bs[64 * 64];
  f32x4 acc[4] = {};
  const short* nb = node_bf + (size_t)b * KN * BH;
  stage_nat(T + (size_t)head * BS * KN * KN + (size_t)b * KN * KN, KN, As, tid);
  stage_tr(nb + d0, BH, Bs, tid);
  __syncthreads();
  mfma64(As, Bs, acc, lane, m0);
  short* CBh = CB_bf + (size_t)head * BS * KN * BH;
#pragma unroll
  for (int f = 0; f < 4; ++f) {
    int d = d0 + f * 16 + (lane & 15);
#pragma unroll
    for (int e = 0; e < 4; ++e) {
      int c = m0 + (lane >> 4) * 4 + e;
      CBh[((size_t)b * KN + c) * BH + d] = f2bf(bf2f(nb[(size_t)c * BH + d]) * acc[f][e]);
    }
  }
}

// ---------------- proj as one big GEMM: feat[16384 x 2048] @ prjT -> H ----------------
// 128row x 128o tile, K=2048, gload_lds single-buffer (k_blk structure, proven R8).
// grid 1024: xcd-chunked; rows contiguous (no gather).
__global__ void k_proj_big(const short* __restrict__ node_bf, const short* __restrict__ A_bf,
                           const short* __restrict__ CA_bf, const short* __restrict__ CB_bf,
                           const short* __restrict__ prjT,
                           short* __restrict__ Hno, short* __restrict__ Hna) {
  const int l = blockIdx.x;            // 1024
  const int xcd = l & 7;
  const int u = l >> 3;                // 0..127
  const int head = u & 1;
  const int o0 = ((u >> 1) & 3) * 128;
  const int mt = xcd * 16 + (u >> 3);  // 0..127
  const int r0 = mt * 128;
  const size_t hk = (size_t)head * BS * KN * BH;
  const int tid = threadIdx.x, lane = tid & 63, wave = tid >> 6;
  const int l15 = lane & 15, g4 = lane >> 4;
  const int m0 = wave * 32;
  __shared__ __align__(16) short As[128 * 64];   // 128 rows x 64 k (16 KB)
  __shared__ __align__(16) short Bs[128 * 64];   // 128 o    x 64 k (16 KB)
  f32x4 acc[16] = {};
  const short* segs[4] = {node_bf, A_bf + hk, CA_bf + hk, CB_bf + hk};
  const short* Bpanel = prjT + (size_t)head * BH * 2048 + (size_t)o0 * 2048;
  const int lr = lane >> 3;   // row within 8-row call
  const int ls = lane & 7;    // 16B slot within row

  for (int t = 0; t < 32; ++t) {
    const int kk = t * 64;
    const short* Aseg = segs[kk >> 9] + (size_t)r0 * BH + (kk & 511);
#pragma unroll
    for (int c = 0; c < 4; ++c) {
      int row = wave * 32 + c * 8 + lr;
      int sw = ls ^ ((row ^ (row >> 3)) & 7);
      gl_lds16(Aseg + (size_t)row * BH + sw * 8, As + (wave * 32 + c * 8) * 64);
    }
#pragma unroll
    for (int c = 0; c < 4; ++c) {
      int row = wave * 32 + c * 8 + lr;
      int sw = ls ^ ((row ^ (row >> 3)) & 7);
      gl_lds16(Bpanel + (size_t)row * 2048 + kk + sw * 8, Bs + (wave * 32 + c * 8) * 64);
    }
    __syncthreads();
#pragma unroll
    for (int kb2 = 0; kb2 < 2; ++kb2) {
      int k16 = kb2 * 32 + g4 * 8;
#pragma unroll
      for (int mi = 0; mi < 2; ++mi) {
        int arow = m0 + mi * 16 + l15;
        bf16x8 af = *(const bf16x8*)((const char*)As + SWZ(arow, arow * 128 + k16 * 2));
#pragma unroll
        for (int f = 0; f < 8; ++f) {
          int nrow = f * 16 + l15;
          bf16x8 bfr = *(const bf16x8*)((const char*)Bs + SWZ(nrow, nrow * 128 + k16 * 2));
          acc[mi * 8 + f] = __builtin_amdgcn_mfma_f32_16x16x32_bf16(af, bfr, acc[mi * 8 + f], 0, 0, 0);
        }
      }
    }
    __syncthreads();
  }
  short* H = head ? Hna : Hno;
#pragma unroll
  for (int mi = 0; mi < 2; ++mi) {
#pragma unroll
    for (int f = 0; f < 8; ++f) {
      int o = o0 + f * 16 + l15;
#pragma unroll
      for (int e = 0; e < 4; ++e) {
        int row = r0 + m0 + mi * 16 + g4 * 4 + e;
        H[(size_t)row * BH + o] = f2bf(acc[mi * 8 + f][e]);
      }
    }
  }
}

// Grouped GEMM, full K=1536, no atomics (proven R8). Tile 64b x 128o, grid 1024.
__global__ void k_blk_mfma(const short* __restrict__ Hno, const short* __restrict__ Hna,
                           const short* __restrict__ node_bf, const float* __restrict__ rew,
                           const short* __restrict__ WT, const float* __restrict__ W,
                           const float* __restrict__ bias, float* __restrict__ out) {
  const int l = blockIdx.x;            // 1024
  const int xcd = l & 7;
  const int idx = l >> 3;              // 0..127
  const int kb = xcd * 8 + (idx & 7);
  const int tile = idx >> 3;           // 0..15
  const int b0 = (tile & 3) * 64, o0 = (tile >> 2) * 128;
  const int tid = threadIdx.x, lane = tid & 63, wave = tid >> 6;
  const int l15 = lane & 15, g4 = lane >> 4;
  const int m0 = wave * 16;
  __shared__ __align__(16) short As[64 * 64];
  __shared__ __align__(16) short Bs[128 * 64];
  f32x4 acc[8] = {};
  const short* segs[3] = {Hno, Hna, node_bf};
  const short* Bpanel = WT + ((size_t)kb * BH + o0) * 1536;
  const int lr = lane >> 3;
  const int ls = lane & 7;

  for (int t = 0; t < 24; ++t) {
    const int kk = t * 64;
    const short* Aseg = segs[kk >> 9] + (size_t)kb * BH + (kk & 511);
#pragma unroll
    for (int c = 0; c < 2; ++c) {
      int row = wave * 16 + c * 8 + lr;
      int sw = ls ^ ((row ^ (row >> 3)) & 7);
      gl_lds16(Aseg + ((size_t)(b0 + row) * KN) * BH + sw * 8,
               As + (wave * 16 + c * 8) * 64);
    }
#pragma unroll
    for (int c = 0; c < 4; ++c) {
      int row = wave * 32 + c * 8 + lr;
      int sw = ls ^ ((row ^ (row >> 3)) & 7);
      gl_lds16(Bpanel + (size_t)row * 1536 + kk + sw * 8,
               Bs + (wave * 32 + c * 8) * 64);
    }
    __syncthreads();
#pragma unroll
    for (int kb2 = 0; kb2 < 2; ++kb2) {
      int k16 = kb2 * 32 + g4 * 8;
      int arow = m0 + l15;
      bf16x8 af = *(const bf16x8*)((const char*)As + SWZ(arow, arow * 128 + k16 * 2));
#pragma unroll
      for (int f = 0; f < 8; ++f) {
        int nrow = f * 16 + l15;
        bf16x8 bfr = *(const bf16x8*)((const char*)Bs + SWZ(nrow, nrow * 128 + k16 * 2));
        acc[f] = __builtin_amdgcn_mfma_f32_16x16x32_bf16(af, bfr, acc[f], 0, 0, 0);
      }
    }
    __syncthreads();
  }
  const float* Wrow = W + (size_t)kb * SUB_IN * BH + (size_t)1536 * BH;
  const float* bkb = bias + kb * BH;
#pragma unroll
  for (int f = 0; f < 8; ++f) {
    int o = o0 + f * 16 + l15;
    float wr = Wrow[o];
    float bv = bkb[o];
#pragma unroll
    for (int e = 0; e < 4; ++e) {
      int bb = b0 + m0 + g4 * 4 + e;
      out[((size_t)bb * KN + kb) * BH + o] = acc[f][e] + rew[bb] * wr + bv;
    }
  }
}

extern "C" void kernel_launch(void* const* d_in, const int* in_sizes, int n_in,
                              void* d_out, int out_size, void* d_ws, size_t ws_size,
                              hipStream_t stream) {
  (void)in_sizes; (void)n_in; (void)out_size; (void)ws_size;
  const float* act   = (const float*)d_in[0];
  const float* obs   = (const float*)d_in[1];
  const float* amask = (const float*)d_in[2];
  const float* omask = (const float*)d_in[3];
  const float* rew   = (const float*)d_in[4];
  const float* node  = (const float*)d_in[5];
  const float* nmask = (const float*)d_in[6];
  const float* w4C_o = (const float*)d_in[7];
  const float* w4Q_o = (const float*)d_in[8];
  const float* w4m_o = (const float*)d_in[9];
  const float* bias_o= (const float*)d_in[10];
  const float* w4C_a = (const float*)d_in[11];
  const float* w4Q_a = (const float*)d_in[12];
  const float* w4m_a = (const float*)d_in[13];
  const float* bias_a= (const float*)d_in[14];
  const float* prj_o = (const float*)d_in[15];
  const float* prj_a = (const float*)d_in[16];
  const float* blkW  = (const float*)d_in[17];
  const float* blkb  = (const float*)d_in[18];
  float* out = (float*)d_out;

  char* wsb = (char*)d_ws;
  auto alloc = [&](size_t bytes) { char* p = wsb; wsb += (bytes + 255) & ~255ull; return p; };
  const size_t NKB = (size_t)BS * KN * BH;   // 8.4M elems
  const size_t NQB = (size_t)BS * LQ * BH;   // 33.6M elems
  const size_t NS  = (size_t)BS * KN * LQ;   // 4.2M elems
  // no aliasing: ws is ~806 MB, total below ~470 MB
  short* node_bf = (short*)alloc(NKB * 2);
  short* Cw_o    = (short*)alloc(NKB * 2);
  short* Cw_a    = (short*)alloc(NKB * 2);
  short* prjT    = (short*)alloc((size_t)2 * BH * 2048 * 2);
  short* Q_bf    = (short*)alloc((size_t)2 * NQB * 2);
  short* S1      = (short*)alloc((size_t)2 * NS * 2);
  short* S2      = (short*)alloc((size_t)2 * NS * 2);
  short* A_bf    = (short*)alloc((size_t)2 * NKB * 2);
  short* CA_bf   = (short*)alloc((size_t)2 * NKB * 2);
  short* CB_bf   = (short*)alloc((size_t)2 * NKB * 2);
  short* T_bf    = (short*)alloc((size_t)2 * BS * KN * KN * 2);
  short* Hno     = (short*)alloc(NKB * 2);
  short* Hna     = (short*)alloc(NKB * 2);
  short* WT      = (short*)alloc((size_t)KN * BH * 1536 * 2);
  float* cw      = (float*)alloc((size_t)2 * BS * KN * 4);
  float* qw      = (float*)alloc((size_t)2 * BS * LQ * 4);

  k_cvtQ2<<<dim3(BS * LQ / 4, 2), 256, 0, stream>>>(obs, act, w4Q_o, w4Q_a, Q_bf, qw);
  k_cvtC2<<<dim3(BS * KN / 4), 256, 0, stream>>>(node, w4C_o, w4C_a, w4m_o, w4m_a,
                                                 node_bf, Cw_o, Cw_a, cw, cw + BS * KN);
  k_prjT<<<dim3(64, 16, 2), 256, 0, stream>>>(prj_o, prj_a, prjT);
  k_WT<<<dim3(48, 16, 64), 256, 0, stream>>>(blkW, WT);
  k_score2<<<dim3(BS, 2), 512, 0, stream>>>(Cw_o, Cw_a, Q_bf, cw, qw, bias_o, bias_a,
                                            nmask, omask, amask, S1, S2);
  k_gemm_A_mfma<<<dim3(BS, BH / 64, 2), 256, 0, stream>>>(S1, Q_bf, node_bf, A_bf, CA_bf);
  k_gemm_T_mfma<<<dim3(BS, 2), 256, 0, stream>>>(S1, S2, T_bf);
  k_gemm_B_mfma<<<dim3(BS, BH / 64, 2), 256, 0, stream>>>(T_bf, node_bf, CB_bf);
  k_proj_big<<<dim3(1024), 256, 0, stream>>>(node_bf, A_bf, CA_bf, CB_bf, prjT, Hno, Hna);
  k_blk_mfma<<<dim3(1024), 256, 0, stream>>>(Hno, Hna, node_bf, rew, WT, blkW, blkb, out);
}